// Round 2
// baseline (1052.490 us; speedup 1.0000x reference)
//
#include <hip/hip_runtime.h>
#include <hip/hip_bf16.h>
#include <math.h>

// Problem constants
#define B_ 2
#define L_ 1024
#define D_ 1024
#define D_INNER 2048
#define DT_RANK 64
#define N_STATE 16
#define NC 16          // scan chunks
#define LC 64          // L_/NC

// ---------------- LayerNorm ----------------
__global__ __launch_bounds__(256) void ln_kernel(const float* __restrict__ x,
                                                 const float* __restrict__ w,
                                                 const float* __restrict__ b,
                                                 float* __restrict__ out) {
  int row = blockIdx.x;            // 0..B_*L_-1
  int tid = threadIdx.x;           // 256 threads, 4 floats each
  const float* xr = x + (size_t)row * D_;
  float4 v = ((const float4*)xr)[tid];
  float s  = v.x + v.y + v.z + v.w;
  float s2 = v.x*v.x + v.y*v.y + v.z*v.z + v.w*v.w;
  #pragma unroll
  for (int off = 32; off > 0; off >>= 1) {
    s  += __shfl_down(s, off);
    s2 += __shfl_down(s2, off);
  }
  __shared__ float ss[4], ss2[4];
  int wid = tid >> 6, lane = tid & 63;
  if (lane == 0) { ss[wid] = s; ss2[wid] = s2; }
  __syncthreads();
  if (tid == 0) {
    float a  = ss[0] + ss[1] + ss[2] + ss[3];
    float a2 = ss2[0] + ss2[1] + ss2[2] + ss2[3];
    ss[0]  = a  * (1.0f / D_);
    ss2[0] = a2 * (1.0f / D_);
  }
  __syncthreads();
  float mu = ss[0];
  float var = ss2[0] - mu * mu;
  float rstd = rsqrtf(var + 1e-5f);
  float4 wv = ((const float4*)w)[tid];
  float4 bv = ((const float4*)b)[tid];
  float4 o;
  o.x = (v.x - mu) * rstd * wv.x + bv.x;
  o.y = (v.y - mu) * rstd * wv.y + bv.y;
  o.z = (v.z - mu) * rstd * wv.z + bv.z;
  o.w = (v.w - mu) * rstd * wv.w + bv.w;
  ((float4*)(out + (size_t)row * D_))[tid] = o;
}

// ---------------- Tiled fp32 GEMM: C[M][N] = A[M][K] * B[N][K]^T ----------------
// EPI: 0 = plain, 1 = softplus(acc + ep0[col]), 2 = acc + ep0[row*ldc+col] (residual)
__device__ __forceinline__ float softplus_f(float v) {
  return (v > 20.0f) ? v : log1pf(__expf(v));
}

template<int EPI>
__global__ __launch_bounds__(256) void gemm_nt(const float* __restrict__ A, int lda,
                                               const float* __restrict__ Bm, int ldb,
                                               float* __restrict__ C, int ldc,
                                               int M, int N, int K,
                                               const float* __restrict__ ep0) {
  const int BM = 128, BN = 128, BK = 16;
  __shared__ float As[BK][BM + 4];
  __shared__ float Bs[BK][BN + 4];
  int bm = blockIdx.y * BM;
  int bn = blockIdx.x * BN;
  int tid = threadIdx.x;
  int tx = tid & 15, ty = tid >> 4;     // 16x16 threads, each 8x8 outputs
  float acc[8][8];
  #pragma unroll
  for (int i = 0; i < 8; ++i)
    #pragma unroll
    for (int j = 0; j < 8; ++j) acc[i][j] = 0.0f;

  for (int k0 = 0; k0 < K; k0 += BK) {
    // stage A tile (128 rows x 16 cols), 512 float4s / 256 threads
    #pragma unroll
    for (int p = tid; p < 512; p += 256) {
      int row = p >> 2, kq = (p & 3) * 4;
      float4 v = *(const float4*)&A[(size_t)(bm + row) * lda + k0 + kq];
      As[kq + 0][row] = v.x; As[kq + 1][row] = v.y;
      As[kq + 2][row] = v.z; As[kq + 3][row] = v.w;
    }
    // stage B tile (128 rows x 16 cols), guard rows >= N
    #pragma unroll
    for (int p = tid; p < 512; p += 256) {
      int row = p >> 2, kq = (p & 3) * 4;
      float4 v = make_float4(0.f, 0.f, 0.f, 0.f);
      if (bn + row < N) v = *(const float4*)&Bm[(size_t)(bn + row) * ldb + k0 + kq];
      Bs[kq + 0][row] = v.x; Bs[kq + 1][row] = v.y;
      Bs[kq + 2][row] = v.z; Bs[kq + 3][row] = v.w;
    }
    __syncthreads();
    #pragma unroll
    for (int kk = 0; kk < BK; ++kk) {
      float4 a0 = *(const float4*)&As[kk][ty * 8];
      float4 a1 = *(const float4*)&As[kk][ty * 8 + 4];
      float4 b0 = *(const float4*)&Bs[kk][tx * 8];
      float4 b1 = *(const float4*)&Bs[kk][tx * 8 + 4];
      float a[8] = {a0.x, a0.y, a0.z, a0.w, a1.x, a1.y, a1.z, a1.w};
      float b[8] = {b0.x, b0.y, b0.z, b0.w, b1.x, b1.y, b1.z, b1.w};
      #pragma unroll
      for (int i = 0; i < 8; ++i)
        #pragma unroll
        for (int j = 0; j < 8; ++j)
          acc[i][j] = fmaf(a[i], b[j], acc[i][j]);
    }
    __syncthreads();
  }

  // epilogue
  #pragma unroll
  for (int i = 0; i < 8; ++i) {
    int r = bm + ty * 8 + i;
    #pragma unroll
    for (int jq = 0; jq < 2; ++jq) {
      int c = bn + tx * 8 + jq * 4;
      if (c >= N) continue;
      float4 o;
      float* pa = &acc[i][jq * 4];
      if (EPI == 0) {
        o = make_float4(pa[0], pa[1], pa[2], pa[3]);
      } else if (EPI == 1) {
        o.x = softplus_f(pa[0] + ep0[c + 0]);
        o.y = softplus_f(pa[1] + ep0[c + 1]);
        o.z = softplus_f(pa[2] + ep0[c + 2]);
        o.w = softplus_f(pa[3] + ep0[c + 3]);
      } else {
        const float4 rv = *(const float4*)&ep0[(size_t)r * ldc + c];
        o = make_float4(pa[0] + rv.x, pa[1] + rv.y, pa[2] + rv.z, pa[3] + rv.w);
      }
      *(float4*)&C[(size_t)r * ldc + c] = o;
    }
  }
}

// ---------------- Conv1d (depthwise, K=4, causal) + SiLU ----------------
__global__ __launch_bounds__(256) void conv_silu_kernel(const float* __restrict__ xz,
                                                        const float* __restrict__ Wc,
                                                        const float* __restrict__ bc,
                                                        float* __restrict__ xc) {
  int idx = blockIdx.x * 256 + threadIdx.x;  // B_*L_*D_INNER
  int e = idx & (D_INNER - 1);
  int t = (idx >> 11) & (L_ - 1);
  int b = idx >> 21;
  float acc = bc[e];
  float w0 = Wc[e * 4 + 0], w1 = Wc[e * 4 + 1], w2 = Wc[e * 4 + 2], w3 = Wc[e * 4 + 3];
  const float* base = xz + (size_t)b * L_ * 4096 + e;   // xs = first half of xz row
  if (t >= 3) acc = fmaf(base[(size_t)(t - 3) * 4096], w0, acc);
  if (t >= 2) acc = fmaf(base[(size_t)(t - 2) * 4096], w1, acc);
  if (t >= 1) acc = fmaf(base[(size_t)(t - 1) * 4096], w2, acc);
  acc = fmaf(base[(size_t)t * 4096], w3, acc);
  xc[idx] = acc / (1.0f + __expf(-acc));   // silu
}

// ---------------- Scan phase 1: per-chunk (prod dA, local state) ----------------
__global__ __launch_bounds__(256) void scan1_kernel(const float* __restrict__ delta,
                                                    const float* __restrict__ xc,
                                                    const float* __restrict__ dbl,
                                                    const float* __restrict__ A_log,
                                                    float* __restrict__ P,
                                                    float* __restrict__ Q) {
  int e = blockIdx.x * 256 + threadIdx.x;
  int b = blockIdx.y, c = blockIdx.z;
  float An[N_STATE];
  #pragma unroll
  for (int q = 0; q < 4; ++q) {
    float4 v = *(const float4*)&A_log[(size_t)e * N_STATE + q * 4];
    An[q*4+0] = -__expf(v.x); An[q*4+1] = -__expf(v.y);
    An[q*4+2] = -__expf(v.z); An[q*4+3] = -__expf(v.w);
  }
  float h[N_STATE], p[N_STATE];
  #pragma unroll
  for (int n = 0; n < N_STATE; ++n) { h[n] = 0.f; p[n] = 1.f; }

  const size_t row0 = ((size_t)b * L_ + c * LC) * D_INNER + e;
  const float* dbase = dbl + ((size_t)b * L_ + c * LC) * 96;

  float dlt = delta[row0];
  float xcv = xc[row0];
  float4 Bq[4];
  #pragma unroll
  for (int q = 0; q < 4; ++q) Bq[q] = *(const float4*)(dbase + 64 + q * 4);

  for (int tt = 0; tt < LC; ++tt) {
    // prefetch next step
    float ndlt = 0.f, nxcv = 0.f;
    float4 nBq[4] = {make_float4(0,0,0,0), make_float4(0,0,0,0),
                     make_float4(0,0,0,0), make_float4(0,0,0,0)};
    if (tt + 1 < LC) {
      ndlt = delta[row0 + (size_t)(tt + 1) * D_INNER];
      nxcv = xc[row0 + (size_t)(tt + 1) * D_INNER];
      #pragma unroll
      for (int q = 0; q < 4; ++q) nBq[q] = *(const float4*)(dbase + (tt + 1) * 96 + 64 + q * 4);
    }
    float dbx = dlt * xcv;
    float Bv[N_STATE] = {Bq[0].x,Bq[0].y,Bq[0].z,Bq[0].w, Bq[1].x,Bq[1].y,Bq[1].z,Bq[1].w,
                         Bq[2].x,Bq[2].y,Bq[2].z,Bq[2].w, Bq[3].x,Bq[3].y,Bq[3].z,Bq[3].w};
    #pragma unroll
    for (int n = 0; n < N_STATE; ++n) {
      float da = __expf(dlt * An[n]);
      h[n] = fmaf(da, h[n], dbx * Bv[n]);
      p[n] *= da;
    }
    dlt = ndlt; xcv = nxcv;
    #pragma unroll
    for (int q = 0; q < 4; ++q) Bq[q] = nBq[q];
  }
  size_t o = ((size_t)(c * B_ + b) * N_STATE) * D_INNER + e;
  #pragma unroll
  for (int n = 0; n < N_STATE; ++n) {
    P[o + (size_t)n * D_INNER] = p[n];
    Q[o + (size_t)n * D_INNER] = h[n];
  }
}

// ---------------- Scan phase 2: combine chunk states ----------------
__global__ __launch_bounds__(256) void scan2_kernel(const float* __restrict__ P,
                                                    const float* __restrict__ Q,
                                                    float* __restrict__ Hinit) {
  int idx = blockIdx.x * 256 + threadIdx.x;  // B_*N_STATE*D_INNER = 65536
  float H = 0.f;
  #pragma unroll
  for (int c = 0; c < NC; ++c) {
    size_t o = (size_t)c * (B_ * N_STATE * D_INNER) + idx;
    Hinit[o] = H;
    H = fmaf(P[o], H, Q[o]);
  }
}

// ---------------- Scan phase 3: replay + y output (fused gate) ----------------
__global__ __launch_bounds__(256) void scan3_kernel(const float* __restrict__ delta,
                                                    const float* __restrict__ xc,
                                                    const float* __restrict__ dbl,
                                                    const float* __restrict__ A_log,
                                                    const float* __restrict__ Hinit,
                                                    const float* __restrict__ xz,
                                                    const float* __restrict__ Dsk,
                                                    float* __restrict__ y) {
  int e = blockIdx.x * 256 + threadIdx.x;
  int b = blockIdx.y, c = blockIdx.z;
  float An[N_STATE];
  #pragma unroll
  for (int q = 0; q < 4; ++q) {
    float4 v = *(const float4*)&A_log[(size_t)e * N_STATE + q * 4];
    An[q*4+0] = -__expf(v.x); An[q*4+1] = -__expf(v.y);
    An[q*4+2] = -__expf(v.z); An[q*4+3] = -__expf(v.w);
  }
  float h[N_STATE];
  {
    size_t o = (size_t)c * (B_ * N_STATE * D_INNER) + (size_t)b * (N_STATE * D_INNER) + e;
    #pragma unroll
    for (int n = 0; n < N_STATE; ++n) h[n] = Hinit[o + (size_t)n * D_INNER];
  }
  float dskip = Dsk[e];
  const size_t row0 = ((size_t)b * L_ + c * LC) * D_INNER + e;
  const size_t zrow0 = ((size_t)b * L_ + c * LC) * 4096 + D_INNER + e;
  const float* dbase = dbl + ((size_t)b * L_ + c * LC) * 96;

  float dlt = delta[row0];
  float xcv = xc[row0];
  float zv  = xz[zrow0];
  float4 Bq[4], Cq[4];
  #pragma unroll
  for (int q = 0; q < 4; ++q) {
    Bq[q] = *(const float4*)(dbase + 64 + q * 4);
    Cq[q] = *(const float4*)(dbase + 80 + q * 4);
  }

  for (int tt = 0; tt < LC; ++tt) {
    float ndlt = 0.f, nxcv = 0.f, nzv = 0.f;
    float4 nBq[4] = {make_float4(0,0,0,0), make_float4(0,0,0,0),
                     make_float4(0,0,0,0), make_float4(0,0,0,0)};
    float4 nCq[4] = {make_float4(0,0,0,0), make_float4(0,0,0,0),
                     make_float4(0,0,0,0), make_float4(0,0,0,0)};
    if (tt + 1 < LC) {
      ndlt = delta[row0 + (size_t)(tt + 1) * D_INNER];
      nxcv = xc[row0 + (size_t)(tt + 1) * D_INNER];
      nzv  = xz[zrow0 + (size_t)(tt + 1) * 4096];
      #pragma unroll
      for (int q = 0; q < 4; ++q) {
        nBq[q] = *(const float4*)(dbase + (tt + 1) * 96 + 64 + q * 4);
        nCq[q] = *(const float4*)(dbase + (tt + 1) * 96 + 80 + q * 4);
      }
    }
    float dbx = dlt * xcv;
    float Bv[N_STATE] = {Bq[0].x,Bq[0].y,Bq[0].z,Bq[0].w, Bq[1].x,Bq[1].y,Bq[1].z,Bq[1].w,
                         Bq[2].x,Bq[2].y,Bq[2].z,Bq[2].w, Bq[3].x,Bq[3].y,Bq[3].z,Bq[3].w};
    float Cv[N_STATE] = {Cq[0].x,Cq[0].y,Cq[0].z,Cq[0].w, Cq[1].x,Cq[1].y,Cq[1].z,Cq[1].w,
                         Cq[2].x,Cq[2].y,Cq[2].z,Cq[2].w, Cq[3].x,Cq[3].y,Cq[3].z,Cq[3].w};
    float yv = 0.f;
    #pragma unroll
    for (int n = 0; n < N_STATE; ++n) {
      float da = __expf(dlt * An[n]);
      h[n] = fmaf(da, h[n], dbx * Bv[n]);
      yv = fmaf(h[n], Cv[n], yv);
    }
    float gate = zv / (1.0f + __expf(-zv));          // silu(z)
    y[row0 + (size_t)tt * D_INNER] = (yv + dskip * xcv) * gate;
    dlt = ndlt; xcv = nxcv; zv = nzv;
    #pragma unroll
    for (int q = 0; q < 4; ++q) { Bq[q] = nBq[q]; Cq[q] = nCq[q]; }
  }
}

// ---------------- launch ----------------
extern "C" void kernel_launch(void* const* d_in, const int* in_sizes, int n_in,
                              void* d_out, int out_size, void* d_ws, size_t ws_size,
                              hipStream_t stream) {
  const float* x       = (const float*)d_in[0];
  const float* ln_w    = (const float*)d_in[1];
  const float* ln_b    = (const float*)d_in[2];
  const float* W_in    = (const float*)d_in[3];
  const float* W_conv  = (const float*)d_in[4];
  const float* b_conv  = (const float*)d_in[5];
  const float* W_xproj = (const float*)d_in[6];
  const float* W_dt    = (const float*)d_in[7];
  const float* b_dt    = (const float*)d_in[8];
  const float* A_log   = (const float*)d_in[9];
  const float* D_skip  = (const float*)d_in[10];
  const float* W_out   = (const float*)d_in[11];
  float* out = (float*)d_out;
  float* ws  = (float*)d_ws;

  const size_t BL = (size_t)B_ * L_;            // 2048
  float* xn    = ws;                            // 2,097,152 floats (dead after GEMM1 -> aliased by P/Q)
  float* xz    = xn + BL * D_;                  // 8,388,608
  float* xc    = xz + BL * 4096;                // 4,194,304
  float* dblb  = xc + BL * D_INNER;             // 196,608
  float* delta = dblb + BL * 96;                // 4,194,304
  float* ybuf  = delta + BL * D_INNER;          // 4,194,304
  float* Hinit = ybuf + BL * D_INNER;           // 1,048,576
  float* P = xn;                                // alias into dead xn region (1,048,576 floats)
  float* Q = xn + 1048576;                      // second half of xn region

  // 1. LayerNorm
  ln_kernel<<<BL, 256, 0, stream>>>(x, ln_w, ln_b, xn);
  // 2. xz = xn @ W_in^T   (M=2048, N=4096, K=1024)
  gemm_nt<0><<<dim3(4096 / 128, BL / 128), 256, 0, stream>>>(
      xn, D_, W_in, D_, xz, 4096, BL, 4096, D_, nullptr);
  // 3. conv + silu -> xc
  conv_silu_kernel<<<(BL * D_INNER) / 256, 256, 0, stream>>>(xz, W_conv, b_conv, xc);
  // 4. dbl = xc @ W_xproj^T  (M=2048, N=96, K=2048)
  gemm_nt<0><<<dim3(1, BL / 128), 256, 0, stream>>>(
      xc, D_INNER, W_xproj, D_INNER, dblb, 96, BL, 96, D_INNER, nullptr);
  // 5. delta = softplus(dt_low @ W_dt^T + b_dt)  (M=2048, N=2048, K=64; A=dbl with lda=96)
  gemm_nt<1><<<dim3(D_INNER / 128, BL / 128), 256, 0, stream>>>(
      dblb, 96, W_dt, DT_RANK, delta, D_INNER, BL, D_INNER, DT_RANK, b_dt);
  // 6. chunked scan
  scan1_kernel<<<dim3(D_INNER / 256, B_, NC), 256, 0, stream>>>(delta, xc, dblb, A_log, P, Q);
  scan2_kernel<<<(B_ * N_STATE * D_INNER) / 256, 256, 0, stream>>>(P, Q, Hinit);
  scan3_kernel<<<dim3(D_INNER / 256, B_, NC), 256, 0, stream>>>(delta, xc, dblb, A_log, Hinit,
                                                                xz, D_skip, ybuf);
  // 7. out = y @ W_out^T + residual  (M=2048, N=1024, K=2048)
  gemm_nt<2><<<dim3(D_ / 128, BL / 128), 256, 0, stream>>>(
      ybuf, D_INNER, W_out, D_INNER, out, D_, BL, D_, D_INNER, x);
}

// Round 4
// 374.455 us; speedup vs baseline: 2.8107x; 2.8107x over previous
//
#include <hip/hip_runtime.h>
#include <math.h>

// Problem constants
#define B_ 2
#define L_ 1024
#define D_ 1024
#define D_INNER 2048
#define DT_RANK 64
#define N_STATE 16
#define NC 16          // scan chunks
#define LC 64          // L_/NC

typedef __attribute__((ext_vector_type(8))) short bf16x8;
typedef __attribute__((ext_vector_type(4))) float f32x4;

// ---- bf16 helpers (bit-level, RNE) ----
__device__ __forceinline__ unsigned short f2bf(float f) {
  unsigned int u = __float_as_uint(f);
  u += 0x7fffu + ((u >> 16) & 1u);
  return (unsigned short)(u >> 16);
}
__device__ __forceinline__ float bf2f(unsigned short s) {
  return __uint_as_float((unsigned int)s << 16);
}

// ---------------- LayerNorm -> bf16 ----------------
__global__ __launch_bounds__(256) void ln_kernel(const float* __restrict__ x,
                                                 const float* __restrict__ w,
                                                 const float* __restrict__ b,
                                                 unsigned short* __restrict__ out) {
  int row = blockIdx.x;            // 0..B_*L_-1
  int tid = threadIdx.x;           // 256 threads, 4 floats each
  const float* xr = x + (size_t)row * D_;
  float4 v = ((const float4*)xr)[tid];
  float s  = v.x + v.y + v.z + v.w;
  float s2 = v.x*v.x + v.y*v.y + v.z*v.z + v.w*v.w;
  #pragma unroll
  for (int off = 32; off > 0; off >>= 1) {
    s  += __shfl_down(s, off);
    s2 += __shfl_down(s2, off);
  }
  __shared__ float ss[4], ss2[4];
  int wid = tid >> 6, lane = tid & 63;
  if (lane == 0) { ss[wid] = s; ss2[wid] = s2; }
  __syncthreads();
  if (tid == 0) {
    float a  = ss[0] + ss[1] + ss[2] + ss[3];
    float a2 = ss2[0] + ss2[1] + ss2[2] + ss2[3];
    ss[0]  = a  * (1.0f / D_);
    ss2[0] = a2 * (1.0f / D_);
  }
  __syncthreads();
  float mu = ss[0];
  float var = ss2[0] - mu * mu;
  float rstd = rsqrtf(var + 1e-5f);
  float4 wv = ((const float4*)w)[tid];
  float4 bv = ((const float4*)b)[tid];
  ushort4 o;
  o.x = f2bf((v.x - mu) * rstd * wv.x + bv.x);
  o.y = f2bf((v.y - mu) * rstd * wv.y + bv.y);
  o.z = f2bf((v.z - mu) * rstd * wv.z + bv.z);
  o.w = f2bf((v.w - mu) * rstd * wv.w + bv.w);
  ((ushort4*)(out + (size_t)row * D_))[tid] = o;
}

// ---------------- fp32 -> bf16 weight convert ----------------
__global__ __launch_bounds__(256) void cvt_bf16_kernel(const float* __restrict__ in,
                                                       unsigned short* __restrict__ out,
                                                       int n4) {
  int i = blockIdx.x * 256 + threadIdx.x;
  if (i >= n4) return;
  float4 v = ((const float4*)in)[i];
  ushort4 o; o.x = f2bf(v.x); o.y = f2bf(v.y); o.z = f2bf(v.z); o.w = f2bf(v.w);
  ((ushort4*)out)[i] = o;
}

// convert W_xproj [96][2048] -> bf16 padded [128][2048] (rows>=96 zero)
__global__ __launch_bounds__(256) void cvt_wxp_kernel(const float* __restrict__ in,
                                                      unsigned short* __restrict__ out) {
  int i = blockIdx.x * 256 + threadIdx.x;        // 65536 threads, 4 elems each
  int row = (i * 4) >> 11;                       // /2048
  ushort4 o = make_ushort4(0, 0, 0, 0);
  if (row < 96) {
    float4 v = ((const float4*)in)[i];
    o.x = f2bf(v.x); o.y = f2bf(v.y); o.z = f2bf(v.z); o.w = f2bf(v.w);
  }
  ((ushort4*)out)[i] = o;
}

// ---------------- bf16 MFMA GEMM: C[M][N] = A[M][K] * B[N][K]^T ----------------
// 128x128 tile, 256 thr (4 waves 2x2), BK=64, global_load_lds(16B) staging.
// EPI: 0 = fp32 C, 1 = bf16 C, 2 = fp32 C + ep0[r*ldc+c] residual
template<int EPI>
__global__ __launch_bounds__(256) void gemm_mfma(const unsigned short* __restrict__ A, int lda,
                                                 const unsigned short* __restrict__ B, int ldb,
                                                 float* __restrict__ Cf,
                                                 unsigned short* __restrict__ Cb,
                                                 int ldc, int Nguard, int K,
                                                 const float* __restrict__ ep0) {
  __shared__ unsigned short As[128 * 64];
  __shared__ unsigned short Bs[128 * 64];
  const int tid = threadIdx.x;
  const int lane = tid & 63;
  const int w = tid >> 6;
  const int wr = w >> 1, wc = w & 1;
  const int bm = blockIdx.y * 128;
  const int bn = blockIdx.x * 128;
  const int l16 = lane & 15;
  const int lk = (lane >> 4) * 8;

  f32x4 acc[4][4];
  #pragma unroll
  for (int m = 0; m < 4; ++m)
    #pragma unroll
    for (int n = 0; n < 4; ++n) acc[m][n] = (f32x4){0.f, 0.f, 0.f, 0.f};

  for (int k0 = 0; k0 < K; k0 += 64) {
    #pragma unroll
    for (int i = 0; i < 4; ++i) {
      int p = (i * 256 + tid) * 16;        // byte offset in 16KB tile
      int r = p >> 7;                      // 128 B per row (64 bf16)
      int cb = (p & 127) >> 1;             // element col
      const unsigned short* ga = A + (size_t)(bm + r) * lda + k0 + cb;
      __builtin_amdgcn_global_load_lds(
          (const __attribute__((address_space(1))) void*)ga,
          (__attribute__((address_space(3))) void*)(As + (p >> 1)), 16, 0, 0);
      const unsigned short* gb = B + (size_t)(bn + r) * ldb + k0 + cb;
      __builtin_amdgcn_global_load_lds(
          (const __attribute__((address_space(1))) void*)gb,
          (__attribute__((address_space(3))) void*)(Bs + (p >> 1)), 16, 0, 0);
    }
    __syncthreads();
    #pragma unroll
    for (int ks = 0; ks < 2; ++ks) {
      bf16x8 af[4], bfr[4];
      #pragma unroll
      for (int m = 0; m < 4; ++m)
        af[m] = *(const bf16x8*)(As + (wr * 64 + m * 16 + l16) * 64 + ks * 32 + lk);
      #pragma unroll
      for (int n = 0; n < 4; ++n)
        bfr[n] = *(const bf16x8*)(Bs + (wc * 64 + n * 16 + l16) * 64 + ks * 32 + lk);
      #pragma unroll
      for (int m = 0; m < 4; ++m)
        #pragma unroll
        for (int n = 0; n < 4; ++n)
          acc[m][n] = __builtin_amdgcn_mfma_f32_16x16x32_bf16(af[m], bfr[n], acc[m][n], 0, 0, 0);
    }
    __syncthreads();
  }

  // epilogue: C row = (lane>>4)*4 + reg, col = lane&15 (per-fragment)
  const int crow0 = bm + wr * 64 + (lane >> 4) * 4;
  const int ccol0 = bn + wc * 64 + l16;
  #pragma unroll
  for (int m = 0; m < 4; ++m) {
    #pragma unroll
    for (int n = 0; n < 4; ++n) {
      int c = ccol0 + n * 16;
      if (c >= Nguard) continue;
      #pragma unroll
      for (int r = 0; r < 4; ++r) {
        int rr = crow0 + m * 16 + r;
        float v = acc[m][n][r];
        if (EPI == 2) v += ep0[(size_t)rr * ldc + c];
        if (EPI == 1) Cb[(size_t)rr * ldc + c] = f2bf(v);
        else          Cf[(size_t)rr * ldc + c] = v;
      }
    }
  }
}

// ---------------- fp32 tiled GEMM (delta path only): C = softplus(A*B^T + bias) ----
__device__ __forceinline__ float softplus_f(float v) {
  return (v > 20.0f) ? v : log1pf(__expf(v));
}

__global__ __launch_bounds__(256) void gemm_nt_sp(const float* __restrict__ A, int lda,
                                                  const float* __restrict__ Bm, int ldb,
                                                  float* __restrict__ C, int ldc,
                                                  int M, int N, int K,
                                                  const float* __restrict__ ep0) {
  const int BM = 128, BN = 128, BK = 16;
  __shared__ float As[BK][BM + 4];
  __shared__ float Bs[BK][BN + 4];
  int bm = blockIdx.y * BM;
  int bn = blockIdx.x * BN;
  int tid = threadIdx.x;
  int tx = tid & 15, ty = tid >> 4;
  float acc[8][8];
  #pragma unroll
  for (int i = 0; i < 8; ++i)
    #pragma unroll
    for (int j = 0; j < 8; ++j) acc[i][j] = 0.0f;

  for (int k0 = 0; k0 < K; k0 += BK) {
    #pragma unroll
    for (int p = tid; p < 512; p += 256) {
      int row = p >> 2, kq = (p & 3) * 4;
      float4 v = *(const float4*)&A[(size_t)(bm + row) * lda + k0 + kq];
      As[kq + 0][row] = v.x; As[kq + 1][row] = v.y;
      As[kq + 2][row] = v.z; As[kq + 3][row] = v.w;
    }
    #pragma unroll
    for (int p = tid; p < 512; p += 256) {
      int row = p >> 2, kq = (p & 3) * 4;
      float4 v = make_float4(0.f, 0.f, 0.f, 0.f);
      if (bn + row < N) v = *(const float4*)&Bm[(size_t)(bn + row) * ldb + k0 + kq];
      Bs[kq + 0][row] = v.x; Bs[kq + 1][row] = v.y;
      Bs[kq + 2][row] = v.z; Bs[kq + 3][row] = v.w;
    }
    __syncthreads();
    #pragma unroll
    for (int kk = 0; kk < BK; ++kk) {
      float4 a0 = *(const float4*)&As[kk][ty * 8];
      float4 a1 = *(const float4*)&As[kk][ty * 8 + 4];
      float4 b0 = *(const float4*)&Bs[kk][tx * 8];
      float4 b1 = *(const float4*)&Bs[kk][tx * 8 + 4];
      float a[8] = {a0.x, a0.y, a0.z, a0.w, a1.x, a1.y, a1.z, a1.w};
      float b[8] = {b0.x, b0.y, b0.z, b0.w, b1.x, b1.y, b1.z, b1.w};
      #pragma unroll
      for (int i = 0; i < 8; ++i)
        #pragma unroll
        for (int j = 0; j < 8; ++j)
          acc[i][j] = fmaf(a[i], b[j], acc[i][j]);
    }
    __syncthreads();
  }
  #pragma unroll
  for (int i = 0; i < 8; ++i) {
    int r = bm + ty * 8 + i;
    #pragma unroll
    for (int jq = 0; jq < 2; ++jq) {
      int c = bn + tx * 8 + jq * 4;
      if (c >= N) continue;
      float* pa = &acc[i][jq * 4];
      float4 o;
      o.x = softplus_f(pa[0] + ep0[c + 0]);
      o.y = softplus_f(pa[1] + ep0[c + 1]);
      o.z = softplus_f(pa[2] + ep0[c + 2]);
      o.w = softplus_f(pa[3] + ep0[c + 3]);
      *(float4*)&C[(size_t)r * ldc + c] = o;
    }
  }
}

// ---------------- Conv1d (depthwise, K=4, causal) + SiLU ----------------
__global__ __launch_bounds__(256) void conv_silu_kernel(const float* __restrict__ xs,
                                                        const float* __restrict__ Wc,
                                                        const float* __restrict__ bc,
                                                        float* __restrict__ xc,
                                                        unsigned short* __restrict__ xcb) {
  int idx = blockIdx.x * 256 + threadIdx.x;  // B_*L_*D_INNER
  int e = idx & (D_INNER - 1);
  int t = (idx >> 11) & (L_ - 1);
  int b = idx >> 21;
  float acc = bc[e];
  float w0 = Wc[e * 4 + 0], w1 = Wc[e * 4 + 1], w2 = Wc[e * 4 + 2], w3 = Wc[e * 4 + 3];
  const float* base = xs + ((size_t)b * L_ + t) * D_INNER + e;
  if (t >= 3) acc = fmaf(base[-3 * D_INNER], w0, acc);
  if (t >= 2) acc = fmaf(base[-2 * D_INNER], w1, acc);
  if (t >= 1) acc = fmaf(base[-1 * D_INNER], w2, acc);
  acc = fmaf(base[0], w3, acc);
  float s = acc / (1.0f + __expf(-acc));   // silu
  xc[idx] = s;
  xcb[idx] = f2bf(s);
}

// ---------------- Scan phase 1: per-chunk (prod dA, local state) ----------------
__global__ __launch_bounds__(256) void scan1_kernel(const float* __restrict__ delta,
                                                    const float* __restrict__ xc,
                                                    const float* __restrict__ dbl,
                                                    const float* __restrict__ A_log,
                                                    float* __restrict__ P,
                                                    float* __restrict__ Q) {
  int e = blockIdx.x * 256 + threadIdx.x;
  int b = blockIdx.y, c = blockIdx.z;
  float An[N_STATE];
  #pragma unroll
  for (int q = 0; q < 4; ++q) {
    float4 v = *(const float4*)&A_log[(size_t)e * N_STATE + q * 4];
    An[q*4+0] = -__expf(v.x); An[q*4+1] = -__expf(v.y);
    An[q*4+2] = -__expf(v.z); An[q*4+3] = -__expf(v.w);
  }
  float h[N_STATE], p[N_STATE];
  #pragma unroll
  for (int n = 0; n < N_STATE; ++n) { h[n] = 0.f; p[n] = 1.f; }

  const size_t row0 = ((size_t)b * L_ + c * LC) * D_INNER + e;
  const float* dbase = dbl + ((size_t)b * L_ + c * LC) * 96;

  float dlt = delta[row0];
  float xcv = xc[row0];
  float4 Bq[4];
  #pragma unroll
  for (int q = 0; q < 4; ++q) Bq[q] = *(const float4*)(dbase + 64 + q * 4);

  for (int tt = 0; tt < LC; ++tt) {
    float ndlt = 0.f, nxcv = 0.f;
    float4 nBq[4] = {make_float4(0,0,0,0), make_float4(0,0,0,0),
                     make_float4(0,0,0,0), make_float4(0,0,0,0)};
    if (tt + 1 < LC) {
      ndlt = delta[row0 + (size_t)(tt + 1) * D_INNER];
      nxcv = xc[row0 + (size_t)(tt + 1) * D_INNER];
      #pragma unroll
      for (int q = 0; q < 4; ++q) nBq[q] = *(const float4*)(dbase + (tt + 1) * 96 + 64 + q * 4);
    }
    float dbx = dlt * xcv;
    float Bv[N_STATE] = {Bq[0].x,Bq[0].y,Bq[0].z,Bq[0].w, Bq[1].x,Bq[1].y,Bq[1].z,Bq[1].w,
                         Bq[2].x,Bq[2].y,Bq[2].z,Bq[2].w, Bq[3].x,Bq[3].y,Bq[3].z,Bq[3].w};
    #pragma unroll
    for (int n = 0; n < N_STATE; ++n) {
      float da = __expf(dlt * An[n]);
      h[n] = fmaf(da, h[n], dbx * Bv[n]);
      p[n] *= da;
    }
    dlt = ndlt; xcv = nxcv;
    #pragma unroll
    for (int q = 0; q < 4; ++q) Bq[q] = nBq[q];
  }
  size_t o = ((size_t)(c * B_ + b) * N_STATE) * D_INNER + e;
  #pragma unroll
  for (int n = 0; n < N_STATE; ++n) {
    P[o + (size_t)n * D_INNER] = p[n];
    Q[o + (size_t)n * D_INNER] = h[n];
  }
}

// ---------------- Scan phase 2: combine chunk states ----------------
__global__ __launch_bounds__(256) void scan2_kernel(const float* __restrict__ P,
                                                    const float* __restrict__ Q,
                                                    float* __restrict__ Hinit) {
  int idx = blockIdx.x * 256 + threadIdx.x;  // B_*N_STATE*D_INNER = 65536
  float H = 0.f;
  #pragma unroll
  for (int c = 0; c < NC; ++c) {
    size_t o = (size_t)c * (B_ * N_STATE * D_INNER) + idx;
    Hinit[o] = H;
    H = fmaf(P[o], H, Q[o]);
  }
}

// ---------------- Scan phase 3: replay + fused gate -> y (bf16) ----------------
__global__ __launch_bounds__(256) void scan3_kernel(const float* __restrict__ delta,
                                                    const float* __restrict__ xc,
                                                    const float* __restrict__ dbl,
                                                    const float* __restrict__ A_log,
                                                    const float* __restrict__ Hinit,
                                                    const unsigned short* __restrict__ zb,
                                                    const float* __restrict__ Dsk,
                                                    unsigned short* __restrict__ y) {
  int e = blockIdx.x * 256 + threadIdx.x;
  int b = blockIdx.y, c = blockIdx.z;
  float An[N_STATE];
  #pragma unroll
  for (int q = 0; q < 4; ++q) {
    float4 v = *(const float4*)&A_log[(size_t)e * N_STATE + q * 4];
    An[q*4+0] = -__expf(v.x); An[q*4+1] = -__expf(v.y);
    An[q*4+2] = -__expf(v.z); An[q*4+3] = -__expf(v.w);
  }
  float h[N_STATE];
  {
    size_t o = (size_t)c * (B_ * N_STATE * D_INNER) + (size_t)b * (N_STATE * D_INNER) + e;
    #pragma unroll
    for (int n = 0; n < N_STATE; ++n) h[n] = Hinit[o + (size_t)n * D_INNER];
  }
  float dskip = Dsk[e];
  const size_t row0 = ((size_t)b * L_ + c * LC) * D_INNER + e;
  const float* dbase = dbl + ((size_t)b * L_ + c * LC) * 96;

  float dlt = delta[row0];
  float xcv = xc[row0];
  float zv  = bf2f(zb[row0]);
  float4 Bq[4], Cq[4];
  #pragma unroll
  for (int q = 0; q < 4; ++q) {
    Bq[q] = *(const float4*)(dbase + 64 + q * 4);
    Cq[q] = *(const float4*)(dbase + 80 + q * 4);
  }

  for (int tt = 0; tt < LC; ++tt) {
    float ndlt = 0.f, nxcv = 0.f, nzv = 0.f;
    float4 nBq[4] = {make_float4(0,0,0,0), make_float4(0,0,0,0),
                     make_float4(0,0,0,0), make_float4(0,0,0,0)};
    float4 nCq[4] = {make_float4(0,0,0,0), make_float4(0,0,0,0),
                     make_float4(0,0,0,0), make_float4(0,0,0,0)};
    if (tt + 1 < LC) {
      ndlt = delta[row0 + (size_t)(tt + 1) * D_INNER];
      nxcv = xc[row0 + (size_t)(tt + 1) * D_INNER];
      nzv  = bf2f(zb[row0 + (size_t)(tt + 1) * D_INNER]);
      #pragma unroll
      for (int q = 0; q < 4; ++q) {
        nBq[q] = *(const float4*)(dbase + (tt + 1) * 96 + 64 + q * 4);
        nCq[q] = *(const float4*)(dbase + (tt + 1) * 96 + 80 + q * 4);
      }
    }
    float dbx = dlt * xcv;
    float Bv[N_STATE] = {Bq[0].x,Bq[0].y,Bq[0].z,Bq[0].w, Bq[1].x,Bq[1].y,Bq[1].z,Bq[1].w,
                         Bq[2].x,Bq[2].y,Bq[2].z,Bq[2].w, Bq[3].x,Bq[3].y,Bq[3].z,Bq[3].w};
    float Cv[N_STATE] = {Cq[0].x,Cq[0].y,Cq[0].z,Cq[0].w, Cq[1].x,Cq[1].y,Cq[1].z,Cq[1].w,
                         Cq[2].x,Cq[2].y,Cq[2].z,Cq[2].w, Cq[3].x,Cq[3].y,Cq[3].z,Cq[3].w};
    float yv = 0.f;
    #pragma unroll
    for (int n = 0; n < N_STATE; ++n) {
      float da = __expf(dlt * An[n]);
      h[n] = fmaf(da, h[n], dbx * Bv[n]);
      yv = fmaf(h[n], Cv[n], yv);
    }
    float gate = zv / (1.0f + __expf(-zv));          // silu(z)
    y[row0 + (size_t)tt * D_INNER] = f2bf((yv + dskip * xcv) * gate);
    dlt = ndlt; xcv = nxcv; zv = nzv;
    #pragma unroll
    for (int q = 0; q < 4; ++q) { Bq[q] = nBq[q]; Cq[q] = nCq[q]; }
  }
}

// ---------------- launch ----------------
extern "C" void kernel_launch(void* const* d_in, const int* in_sizes, int n_in,
                              void* d_out, int out_size, void* d_ws, size_t ws_size,
                              hipStream_t stream) {
  const float* x       = (const float*)d_in[0];
  const float* ln_w    = (const float*)d_in[1];
  const float* ln_b    = (const float*)d_in[2];
  const float* W_in    = (const float*)d_in[3];
  const float* W_conv  = (const float*)d_in[4];
  const float* b_conv  = (const float*)d_in[5];
  const float* W_xproj = (const float*)d_in[6];
  const float* W_dt    = (const float*)d_in[7];
  const float* b_dt    = (const float*)d_in[8];
  const float* A_log   = (const float*)d_in[9];
  const float* D_skip  = (const float*)d_in[10];
  const float* W_out   = (const float*)d_in[11];
  float* out = (float*)d_out;
  float* ws  = (float*)d_ws;

  const size_t BL = (size_t)B_ * L_;            // 2048
  // fp32 region
  float* xs    = ws;                            // BL*2048        = 4,194,304
  float* xc    = xs    + BL * D_INNER;          // 4,194,304
  float* delta = xc    + BL * D_INNER;          // 4,194,304
  float* dblb  = delta + BL * D_INNER;          // BL*96 = 196,608
  // bf16 region (starts 16B-aligned: 12,779,520 floats prefix)
  unsigned short* bz    = (unsigned short*)(dblb + BL * 96);
  unsigned short* xn_b  = bz;                   // 2048*1024  = 2,097,152 bf16
  unsigned short* Win_b = xn_b  + 2097152;      // 4096*1024  = 4,194,304
  unsigned short* z_b   = Win_b + 4194304;      // 2048*2048  = 4,194,304
  unsigned short* xc_b  = z_b   + 4194304;      // 2048*2048  = 4,194,304
  unsigned short* Wxp_b = xc_b  + 4194304;      // 128*2048   = 262,144 (padded)
  unsigned short* y_b   = Wxp_b + 262144;       // 2048*2048  = 4,194,304
  unsigned short* Wout_b= y_b   + 4194304;      // 1024*2048  = 2,097,152
  // P/Q/Hinit alias the xn_b/Win_b region (dead after the two input GEMMs,
  // used only from scan1 onward): 3 × 1,048,576 floats = 3,145,728 floats
  float* P     = (float*)xn_b;
  float* Q     = P + 1048576;
  float* Hinit = Q + 1048576;

  // 1. LayerNorm -> xn_b (bf16)
  ln_kernel<<<BL, 256, 0, stream>>>(x, ln_w, ln_b, xn_b);
  // 2. weight converts
  cvt_bf16_kernel<<<4096, 256, 0, stream>>>(W_in, Win_b, 1048576);
  cvt_bf16_kernel<<<2048, 256, 0, stream>>>(W_out, Wout_b, 524288);
  cvt_wxp_kernel<<<256, 256, 0, stream>>>(W_xproj, Wxp_b);
  // 3. xs = xn @ W_in[:2048]^T  (fp32 out), z = xn @ W_in[2048:]^T (bf16 out)
  gemm_mfma<0><<<dim3(16, 16), 256, 0, stream>>>(xn_b, D_, Win_b, D_,
                                                 xs, nullptr, D_INNER, D_INNER, D_, nullptr);
  gemm_mfma<1><<<dim3(16, 16), 256, 0, stream>>>(xn_b, D_, Win_b + (size_t)D_INNER * D_, D_,
                                                 nullptr, z_b, D_INNER, D_INNER, D_, nullptr);
  // 4. conv + silu -> xc (fp32) + xc_b (bf16)
  conv_silu_kernel<<<(BL * D_INNER) / 256, 256, 0, stream>>>(xs, W_conv, b_conv, xc, xc_b);
  // 5. dbl = xc @ W_xproj^T  (fp32 out, N=96, padded B)
  gemm_mfma<0><<<dim3(1, 16), 256, 0, stream>>>(xc_b, D_INNER, Wxp_b, D_INNER,
                                                dblb, nullptr, 96, 96, D_INNER, nullptr);
  // 6. delta = softplus(dt_low @ W_dt^T + b_dt) (fp32 path)
  gemm_nt_sp<<<dim3(D_INNER / 128, BL / 128), 256, 0, stream>>>(
      dblb, 96, W_dt, DT_RANK, delta, D_INNER, BL, D_INNER, DT_RANK, b_dt);
  // 7. chunked scan
  scan1_kernel<<<dim3(D_INNER / 256, B_, NC), 256, 0, stream>>>(delta, xc, dblb, A_log, P, Q);
  scan2_kernel<<<(B_ * N_STATE * D_INNER) / 256, 256, 0, stream>>>(P, Q, Hinit);
  scan3_kernel<<<dim3(D_INNER / 256, B_, NC), 256, 0, stream>>>(delta, xc, dblb, A_log, Hinit,
                                                                z_b, D_skip, y_b);
  // 8. out = y @ W_out^T + residual
  gemm_mfma<2><<<dim3(8, 16), 256, 0, stream>>>(y_b, D_INNER, Wout_b, D_INNER,
                                                out, nullptr, D_, D_, D_INNER, x);
}

// Round 8
// 278.134 us; speedup vs baseline: 3.7841x; 1.3463x over previous
//
#include <hip/hip_runtime.h>
#include <math.h>

// Problem constants
#define B_ 2
#define L_ 1024
#define D_ 1024
#define D_INNER 2048
#define DT_RANK 64
#define N_STATE 16
#define NC 32          // scan chunks
#define LC 32          // L_/NC

typedef __attribute__((ext_vector_type(8))) short bf16x8;
typedef __attribute__((ext_vector_type(4))) float f32x4;

// ---- bf16 helpers (bit-level, RNE) ----
__device__ __forceinline__ unsigned short f2bf(float f) {
  unsigned int u = __float_as_uint(f);
  u += 0x7fffu + ((u >> 16) & 1u);
  return (unsigned short)(u >> 16);
}
__device__ __forceinline__ float bf2f(unsigned short s) {
  return __uint_as_float((unsigned int)s << 16);
}

// ---------------- LayerNorm -> bf16 ----------------
__global__ __launch_bounds__(256) void ln_kernel(const float* __restrict__ x,
                                                 const float* __restrict__ w,
                                                 const float* __restrict__ b,
                                                 unsigned short* __restrict__ out) {
  int row = blockIdx.x;
  int tid = threadIdx.x;
  const float* xr = x + (size_t)row * D_;
  float4 v = ((const float4*)xr)[tid];
  float s  = v.x + v.y + v.z + v.w;
  float s2 = v.x*v.x + v.y*v.y + v.z*v.z + v.w*v.w;
  #pragma unroll
  for (int off = 32; off > 0; off >>= 1) {
    s  += __shfl_down(s, off);
    s2 += __shfl_down(s2, off);
  }
  __shared__ float ss[4], ss2[4];
  int wid = tid >> 6, lane = tid & 63;
  if (lane == 0) { ss[wid] = s; ss2[wid] = s2; }
  __syncthreads();
  if (tid == 0) {
    float a  = ss[0] + ss[1] + ss[2] + ss[3];
    float a2 = ss2[0] + ss2[1] + ss2[2] + ss2[3];
    ss[0]  = a  * (1.0f / D_);
    ss2[0] = a2 * (1.0f / D_);
  }
  __syncthreads();
  float mu = ss[0];
  float var = ss2[0] - mu * mu;
  float rstd = rsqrtf(var + 1e-5f);
  float4 wv = ((const float4*)w)[tid];
  float4 bv = ((const float4*)b)[tid];
  ushort4 o;
  o.x = f2bf((v.x - mu) * rstd * wv.x + bv.x);
  o.y = f2bf((v.y - mu) * rstd * wv.y + bv.y);
  o.z = f2bf((v.z - mu) * rstd * wv.z + bv.z);
  o.w = f2bf((v.w - mu) * rstd * wv.w + bv.w);
  ((ushort4*)(out + (size_t)row * D_))[tid] = o;
}

// ---------------- fp32 -> bf16 weight convert ----------------
__global__ __launch_bounds__(256) void cvt_bf16_kernel(const float* __restrict__ in,
                                                       unsigned short* __restrict__ out,
                                                       int n4) {
  int i = blockIdx.x * 256 + threadIdx.x;
  if (i >= n4) return;
  float4 v = ((const float4*)in)[i];
  ushort4 o; o.x = f2bf(v.x); o.y = f2bf(v.y); o.z = f2bf(v.z); o.w = f2bf(v.w);
  ((ushort4*)out)[i] = o;
}

// convert W_xproj [96][2048] -> bf16 padded [128][2048] (rows>=96 zero)
__global__ __launch_bounds__(256) void cvt_wxp_kernel(const float* __restrict__ in,
                                                      unsigned short* __restrict__ out) {
  int i = blockIdx.x * 256 + threadIdx.x;
  int row = (i * 4) >> 11;
  ushort4 o = make_ushort4(0, 0, 0, 0);
  if (row < 96) {
    float4 v = ((const float4*)in)[i];
    o.x = f2bf(v.x); o.y = f2bf(v.y); o.z = f2bf(v.z); o.w = f2bf(v.w);
  }
  ((ushort4*)out)[i] = o;
}

// ---------------- bf16 MFMA GEMM: C[M][N] = A[M][K] * B[N][K]^T ----------------
// BMT x 128 tile, 256 thr (4 waves 2x2), BK=64, global_load_lds(16B) staging,
// st-style XOR swizzle (linear LDS dest + inverse-swizzled global source + swizzled read).
// EPI: 2 = fp32 C + ep0 residual; 3 = xz split (c<2048 -> Cf fp32, else Cb bf16);
//      4 = split-K partial (grid.z slices K/16, out to Cf + z*zstride)
template<int EPI, int BMT>
__global__ __launch_bounds__(256) void gemm_mfma(const unsigned short* __restrict__ A, int lda,
                                                 const unsigned short* __restrict__ B, int ldb,
                                                 float* __restrict__ Cf,
                                                 unsigned short* __restrict__ Cb,
                                                 int ldc, int Nguard, int K,
                                                 const float* __restrict__ ep0,
                                                 size_t zstride = 0) {
  __shared__ unsigned short As[BMT * 64];
  __shared__ unsigned short Bs[128 * 64];
  const int tid = threadIdx.x;
  const int lane = tid & 63;
  const int w = tid >> 6;
  const int wr = w >> 1, wc = w & 1;
  const int bm = blockIdx.y * BMT;
  const int bn = blockIdx.x * 128;
  const int l16 = lane & 15;
  constexpr int MW = BMT / 32;           // M-frags per wave

  int kbeg = 0, kend = K;
  if (EPI == 4) {
    int ks = K >> 4;
    kbeg = blockIdx.z * ks;
    kend = kbeg + ks;
    Cf += (size_t)blockIdx.z * zstride;
  }

  f32x4 acc[MW][4];
  #pragma unroll
  for (int m = 0; m < MW; ++m)
    #pragma unroll
    for (int n = 0; n < 4; ++n) acc[m][n] = (f32x4){0.f, 0.f, 0.f, 0.f};

  for (int k0 = kbeg; k0 < kend; k0 += 64) {
    // stage A tile: linear LDS dest, inverse-swizzled global column
    #pragma unroll
    for (int i = 0; i < BMT / 32; ++i) {
      int p = (i * 256 + tid) * 16;        // linear byte offset in tile
      int r = p >> 7;                      // 128 B per row
      int s = (p >> 4) & 7;                // 16B slot in row
      int cb = ((s ^ (r & 7)) << 3);       // swizzled source element col
      const unsigned short* ga = A + (size_t)(bm + r) * lda + k0 + cb;
      __builtin_amdgcn_global_load_lds(
          (const __attribute__((address_space(1))) void*)ga,
          (__attribute__((address_space(3))) void*)(As + (p >> 1)), 16, 0, 0);
    }
    #pragma unroll
    for (int i = 0; i < 4; ++i) {
      int p = (i * 256 + tid) * 16;
      int r = p >> 7;
      int s = (p >> 4) & 7;
      int cb = ((s ^ (r & 7)) << 3);
      const unsigned short* gb = B + (size_t)(bn + r) * ldb + k0 + cb;
      __builtin_amdgcn_global_load_lds(
          (const __attribute__((address_space(1))) void*)gb,
          (__attribute__((address_space(3))) void*)(Bs + (p >> 1)), 16, 0, 0);
    }
    __syncthreads();
    #pragma unroll
    for (int ks = 0; ks < 2; ++ks) {
      const int slot = ks * 4 + (lane >> 4);
      bf16x8 af[MW], bfr[4];
      #pragma unroll
      for (int m = 0; m < MW; ++m) {
        int ar = wr * (BMT / 2) + m * 16 + l16;
        af[m] = *(const bf16x8*)(As + ar * 64 + ((slot ^ (ar & 7)) << 3));
      }
      #pragma unroll
      for (int n = 0; n < 4; ++n) {
        int br = wc * 64 + n * 16 + l16;
        bfr[n] = *(const bf16x8*)(Bs + br * 64 + ((slot ^ (br & 7)) << 3));
      }
      #pragma unroll
      for (int m = 0; m < MW; ++m)
        #pragma unroll
        for (int n = 0; n < 4; ++n)
          acc[m][n] = __builtin_amdgcn_mfma_f32_16x16x32_bf16(af[m], bfr[n], acc[m][n], 0, 0, 0);
    }
    __syncthreads();
  }

  // epilogue: C row = (lane>>4)*4 + reg, col = lane&15 per fragment
  const int crow0 = bm + wr * (BMT / 2) + (lane >> 4) * 4;
  const int ccol0 = bn + wc * 64 + l16;
  #pragma unroll
  for (int m = 0; m < MW; ++m) {
    #pragma unroll
    for (int n = 0; n < 4; ++n) {
      int c = ccol0 + n * 16;
      if (c >= Nguard) continue;
      #pragma unroll
      for (int r = 0; r < 4; ++r) {
        int rr = crow0 + m * 16 + r;
        float v = acc[m][n][r];
        if (EPI == 2) {
          Cf[(size_t)rr * ldc + c] = v + ep0[(size_t)rr * ldc + c];
        } else if (EPI == 3) {
          if (c < D_INNER) Cf[(size_t)rr * D_INNER + c] = v;
          else             Cb[(size_t)rr * D_INNER + (c - D_INNER)] = f2bf(v);
        } else {
          Cf[(size_t)rr * ldc + c] = v;
        }
      }
    }
  }
}

// ---------------- split-K reduce for dbl ----------------
__global__ __launch_bounds__(256) void reduce_dbl_kernel(const float* __restrict__ part,
                                                         float* __restrict__ dblb) {
  int i = blockIdx.x * 256 + threadIdx.x;    // 49152 float4s
  float4 a = ((const float4*)part)[i];
  #pragma unroll
  for (int s = 1; s < 16; ++s) {
    float4 b = ((const float4*)part)[s * 49152 + i];
    a.x += b.x; a.y += b.y; a.z += b.z; a.w += b.w;
  }
  ((float4*)dblb)[i] = a;
}

// ---------------- fp32 tiled GEMM (delta path): C = softplus(A*B^T + bias) ----
__device__ __forceinline__ float softplus_f(float v) {
  return (v > 20.0f) ? v : log1pf(__expf(v));
}

__global__ __launch_bounds__(256) void gemm_nt_sp(const float* __restrict__ A, int lda,
                                                  const float* __restrict__ Bm, int ldb,
                                                  float* __restrict__ C, int ldc,
                                                  int M, int N, int K,
                                                  const float* __restrict__ ep0) {
  const int BM = 128, BN = 128, BK = 16;
  __shared__ float As[BK][BM + 4];
  __shared__ float Bs[BK][BN + 4];
  int bm = blockIdx.y * BM;
  int bn = blockIdx.x * BN;
  int tid = threadIdx.x;
  int tx = tid & 15, ty = tid >> 4;
  float acc[8][8];
  #pragma unroll
  for (int i = 0; i < 8; ++i)
    #pragma unroll
    for (int j = 0; j < 8; ++j) acc[i][j] = 0.0f;

  for (int k0 = 0; k0 < K; k0 += BK) {
    #pragma unroll
    for (int p = tid; p < 512; p += 256) {
      int row = p >> 2, kq = (p & 3) * 4;
      float4 v = *(const float4*)&A[(size_t)(bm + row) * lda + k0 + kq];
      As[kq + 0][row] = v.x; As[kq + 1][row] = v.y;
      As[kq + 2][row] = v.z; As[kq + 3][row] = v.w;
    }
    #pragma unroll
    for (int p = tid; p < 512; p += 256) {
      int row = p >> 2, kq = (p & 3) * 4;
      float4 v = make_float4(0.f, 0.f, 0.f, 0.f);
      if (bn + row < N) v = *(const float4*)&Bm[(size_t)(bn + row) * ldb + k0 + kq];
      Bs[kq + 0][row] = v.x; Bs[kq + 1][row] = v.y;
      Bs[kq + 2][row] = v.z; Bs[kq + 3][row] = v.w;
    }
    __syncthreads();
    #pragma unroll
    for (int kk = 0; kk < BK; ++kk) {
      float4 a0 = *(const float4*)&As[kk][ty * 8];
      float4 a1 = *(const float4*)&As[kk][ty * 8 + 4];
      float4 b0 = *(const float4*)&Bs[kk][tx * 8];
      float4 b1 = *(const float4*)&Bs[kk][tx * 8 + 4];
      float a[8] = {a0.x, a0.y, a0.z, a0.w, a1.x, a1.y, a1.z, a1.w};
      float b[8] = {b0.x, b0.y, b0.z, b0.w, b1.x, b1.y, b1.z, b1.w};
      #pragma unroll
      for (int i = 0; i < 8; ++i)
        #pragma unroll
        for (int j = 0; j < 8; ++j)
          acc[i][j] = fmaf(a[i], b[j], acc[i][j]);
    }
    __syncthreads();
  }
  #pragma unroll
  for (int i = 0; i < 8; ++i) {
    int r = bm + ty * 8 + i;
    #pragma unroll
    for (int jq = 0; jq < 2; ++jq) {
      int c = bn + tx * 8 + jq * 4;
      if (c >= N) continue;
      float* pa = &acc[i][jq * 4];
      float4 o;
      o.x = softplus_f(pa[0] + ep0[c + 0]);
      o.y = softplus_f(pa[1] + ep0[c + 1]);
      o.z = softplus_f(pa[2] + ep0[c + 2]);
      o.w = softplus_f(pa[3] + ep0[c + 3]);
      *(float4*)&C[(size_t)r * ldc + c] = o;
    }
  }
}

// ---------------- Conv1d (depthwise, K=4, causal) + SiLU ----------------
__global__ __launch_bounds__(256) void conv_silu_kernel(const float* __restrict__ xs,
                                                        const float* __restrict__ Wc,
                                                        const float* __restrict__ bc,
                                                        float* __restrict__ xc,
                                                        unsigned short* __restrict__ xcb) {
  int idx = blockIdx.x * 256 + threadIdx.x;
  int e = idx & (D_INNER - 1);
  int t = (idx >> 11) & (L_ - 1);
  float acc = bc[e];
  float w0 = Wc[e * 4 + 0], w1 = Wc[e * 4 + 1], w2 = Wc[e * 4 + 2], w3 = Wc[e * 4 + 3];
  const float* base = xs + (size_t)idx;   // == ((b*L_+t)*D_INNER + e)
  if (t >= 3) acc = fmaf(base[-3 * D_INNER], w0, acc);
  if (t >= 2) acc = fmaf(base[-2 * D_INNER], w1, acc);
  if (t >= 1) acc = fmaf(base[-1 * D_INNER], w2, acc);
  acc = fmaf(base[0], w3, acc);
  float s = acc / (1.0f + __expf(-acc));
  xc[idx] = s;
  xcb[idx] = f2bf(s);
}

// ---------------- Scan phase 1: per-chunk (prod dA, local state) ----------------
__global__ __launch_bounds__(256) void scan1_kernel(const float* __restrict__ delta,
                                                    const float* __restrict__ xc,
                                                    const float* __restrict__ dbl,
                                                    const float* __restrict__ A_log,
                                                    float* __restrict__ P,
                                                    float* __restrict__ Q) {
  int e = blockIdx.x * 256 + threadIdx.x;
  int b = blockIdx.y, c = blockIdx.z;
  const int t0 = (int)(b * L_ + c * LC);

  __shared__ float sB[LC][N_STATE];     // 2 KB
  for (int i = threadIdx.x; i < LC * N_STATE; i += 256) {
    int step = i >> 4, n = i & 15;
    sB[step][n] = dbl[(size_t)(t0 + step) * 96 + 64 + n];
  }
  __syncthreads();

  float An[N_STATE];
  #pragma unroll
  for (int q = 0; q < 4; ++q) {
    float4 v = *(const float4*)&A_log[(size_t)e * N_STATE + q * 4];
    An[q*4+0] = -__expf(v.x); An[q*4+1] = -__expf(v.y);
    An[q*4+2] = -__expf(v.z); An[q*4+3] = -__expf(v.w);
  }
  float h[N_STATE], p[N_STATE];
  #pragma unroll
  for (int n = 0; n < N_STATE; ++n) { h[n] = 0.f; p[n] = 1.f; }

  const size_t row0 = (size_t)t0 * D_INNER + e;
  float dlt = delta[row0];
  float xcv = xc[row0];

  for (int tt = 0; tt < LC; ++tt) {
    float ndlt = 0.f, nxcv = 0.f;
    if (tt + 1 < LC) {
      ndlt = delta[row0 + (size_t)(tt + 1) * D_INNER];
      nxcv = xc[row0 + (size_t)(tt + 1) * D_INNER];
    }
    float dbx = dlt * xcv;
    #pragma unroll
    for (int n = 0; n < N_STATE; ++n) {
      float da = __expf(dlt * An[n]);
      h[n] = fmaf(da, h[n], dbx * sB[tt][n]);
      p[n] *= da;
    }
    dlt = ndlt; xcv = nxcv;
  }
  size_t o = ((size_t)(c * B_ + b) * N_STATE) * D_INNER + e;
  #pragma unroll
  for (int n = 0; n < N_STATE; ++n) {
    P[o + (size_t)n * D_INNER] = p[n];
    Q[o + (size_t)n * D_INNER] = h[n];
  }
}

// ---------------- Scan phase 2: combine chunk states (Hinit in-place in Q) ----
__global__ __launch_bounds__(256) void scan2_kernel(const float* __restrict__ P,
                                                    float* __restrict__ Q) {
  int idx = blockIdx.x * 256 + threadIdx.x;  // B_*N_STATE*D_INNER = 65536
  float H = 0.f;
  #pragma unroll
  for (int c = 0; c < NC; ++c) {
    size_t o = (size_t)c * (B_ * N_STATE * D_INNER) + idx;
    float p = P[o], q = Q[o];
    Q[o] = H;                         // Hinit for chunk c
    H = fmaf(p, H, q);
  }
}

// ---------------- Scan phase 3: replay + fused gate -> y (bf16) ----------------
__global__ __launch_bounds__(256) void scan3_kernel(const float* __restrict__ delta,
                                                    const float* __restrict__ xc,
                                                    const float* __restrict__ dbl,
                                                    const float* __restrict__ A_log,
                                                    const float* __restrict__ Hinit,
                                                    const unsigned short* __restrict__ zb,
                                                    const float* __restrict__ Dsk,
                                                    unsigned short* __restrict__ y) {
  int e = blockIdx.x * 256 + threadIdx.x;
  int b = blockIdx.y, c = blockIdx.z;
  const int t0 = (int)(b * L_ + c * LC);

  __shared__ float sB[LC][N_STATE];     // 2 KB
  __shared__ float sC[LC][N_STATE];     // 2 KB
  for (int i = threadIdx.x; i < LC * N_STATE; i += 256) {
    int step = i >> 4, n = i & 15;
    const float* row = dbl + (size_t)(t0 + step) * 96;
    sB[step][n] = row[64 + n];
    sC[step][n] = row[80 + n];
  }
  __syncthreads();

  float An[N_STATE];
  #pragma unroll
  for (int q = 0; q < 4; ++q) {
    float4 v = *(const float4*)&A_log[(size_t)e * N_STATE + q * 4];
    An[q*4+0] = -__expf(v.x); An[q*4+1] = -__expf(v.y);
    An[q*4+2] = -__expf(v.z); An[q*4+3] = -__expf(v.w);
  }
  float h[N_STATE];
  {
    size_t o = (size_t)c * (B_ * N_STATE * D_INNER) + (size_t)b * (N_STATE * D_INNER) + e;
    #pragma unroll
    for (int n = 0; n < N_STATE; ++n) h[n] = Hinit[o + (size_t)n * D_INNER];
  }
  float dskip = Dsk[e];
  const size_t row0 = (size_t)t0 * D_INNER + e;

  float dlt = delta[row0];
  float xcv = xc[row0];
  float zv  = bf2f(zb[row0]);

  for (int tt = 0; tt < LC; ++tt) {
    float ndlt = 0.f, nxcv = 0.f, nzv = 0.f;
    if (tt + 1 < LC) {
      ndlt = delta[row0 + (size_t)(tt + 1) * D_INNER];
      nxcv = xc[row0 + (size_t)(tt + 1) * D_INNER];
      nzv  = bf2f(zb[row0 + (size_t)(tt + 1) * D_INNER]);
    }
    float dbx = dlt * xcv;
    float yv = 0.f;
    #pragma unroll
    for (int n = 0; n < N_STATE; ++n) {
      float da = __expf(dlt * An[n]);
      h[n] = fmaf(da, h[n], dbx * sB[tt][n]);
      yv = fmaf(h[n], sC[tt][n], yv);
    }
    float gate = zv / (1.0f + __expf(-zv));
    y[row0 + (size_t)tt * D_INNER] = f2bf((yv + dskip * xcv) * gate);
    dlt = ndlt; xcv = nxcv; zv = nzv;
  }
}

// ---------------- launch ----------------
extern "C" void kernel_launch(void* const* d_in, const int* in_sizes, int n_in,
                              void* d_out, int out_size, void* d_ws, size_t ws_size,
                              hipStream_t stream) {
  const float* x       = (const float*)d_in[0];
  const float* ln_w    = (const float*)d_in[1];
  const float* ln_b    = (const float*)d_in[2];
  const float* W_in    = (const float*)d_in[3];
  const float* W_conv  = (const float*)d_in[4];
  const float* b_conv  = (const float*)d_in[5];
  const float* W_xproj = (const float*)d_in[6];
  const float* W_dt    = (const float*)d_in[7];
  const float* b_dt    = (const float*)d_in[8];
  const float* A_log   = (const float*)d_in[9];
  const float* D_skip  = (const float*)d_in[10];
  const float* W_out   = (const float*)d_in[11];
  float* out = (float*)d_out;
  float* ws  = (float*)d_ws;

  const size_t BL = (size_t)B_ * L_;            // 2048
  // fp32 region (12,779,520 floats = 51.1 MB)
  float* xs    = ws;                            // 4,194,304
  float* xc    = xs    + BL * D_INNER;          // 4,194,304
  float* delta = xc    + BL * D_INNER;          // 4,194,304
  float* dblb  = delta + BL * D_INNER;          // 196,608
  // bf16 region (21,233,664 shorts = 42.5 MB)
  unsigned short* xn_b  = (unsigned short*)(dblb + BL * 96);
  unsigned short* Win_b = xn_b  + 2097152;      // 4096*1024
  unsigned short* z_b   = Win_b + 4194304;      // 2048*2048
  unsigned short* xc_b  = z_b   + 4194304;      // 2048*2048
  unsigned short* Wxp_b = xc_b  + 4194304;      // 128*2048 (padded)
  unsigned short* y_b   = Wxp_b + 262144;       // 2048*2048
  unsigned short* Wout_b= y_b   + 4194304;      // 1024*2048
  // Aliases (all dead at use time):
  // P (2,097,152 f) over xn_b + first half of Win_b (dead after input GEMM)
  // Q (2,097,152 f) over xc_b exactly (dead after dbl GEMM); Hinit in-place in Q
  // part (3,145,728 f = 16 x 2048 x 96) over y_b + Wout_b (dead until scan3 / re-cvt)
  float* P    = (float*)xn_b;
  float* Q    = (float*)xc_b;
  float* part = (float*)y_b;

  // 1. LayerNorm -> xn_b
  ln_kernel<<<BL, 256, 0, stream>>>(x, ln_w, ln_b, xn_b);
  // 2. weight converts (W_out converted later, after dbl partials are dead)
  cvt_bf16_kernel<<<4096, 256, 0, stream>>>(W_in, Win_b, 1048576);
  cvt_wxp_kernel<<<256, 256, 0, stream>>>(W_xproj, Wxp_b);
  // 3. merged input GEMM: [xs | z] = xn @ W_in^T  (M=2048, N=4096, K=1024)
  gemm_mfma<3, 128><<<dim3(32, 16), 256, 0, stream>>>(
      xn_b, D_, Win_b, D_, xs, z_b, D_INNER, 4096, D_, nullptr, 0);
  // 4. conv + silu -> xc (fp32) + xc_b (bf16)
  conv_silu_kernel<<<(BL * D_INNER) / 256, 256, 0, stream>>>(xs, W_conv, b_conv, xc, xc_b);
  // 5. dbl = xc @ W_xproj^T  split-K x16 partials (N=96 padded to 128)
  gemm_mfma<4, 128><<<dim3(1, 16, 16), 256, 0, stream>>>(
      xc_b, D_INNER, Wxp_b, D_INNER, part, nullptr, 96, 96, D_INNER, nullptr,
      (size_t)2048 * 96);
  reduce_dbl_kernel<<<192, 256, 0, stream>>>(part, dblb);
  // 6. now safe: convert W_out (overwrites former partial region)
  cvt_bf16_kernel<<<2048, 256, 0, stream>>>(W_out, Wout_b, 524288);
  // 7. delta = softplus(dt_low @ W_dt^T + b_dt) (fp32 path)
  gemm_nt_sp<<<dim3(D_INNER / 128, BL / 128), 256, 0, stream>>>(
      dblb, 96, W_dt, DT_RANK, delta, D_INNER, BL, D_INNER, DT_RANK, b_dt);
  // 8. chunked scan (NC=32)
  scan1_kernel<<<dim3(D_INNER / 256, B_, NC), 256, 0, stream>>>(delta, xc, dblb, A_log, P, Q);
  scan2_kernel<<<(B_ * N_STATE * D_INNER) / 256, 256, 0, stream>>>(P, Q);
  scan3_kernel<<<dim3(D_INNER / 256, B_, NC), 256, 0, stream>>>(delta, xc, dblb, A_log, Q,
                                                                z_b, D_skip, y_b);
  // 9. out = y @ W_out^T + residual  (64x128 tile -> 256 blocks)
  gemm_mfma<2, 64><<<dim3(8, 32), 256, 0, stream>>>(
      y_b, D_INNER, Wout_b, D_INNER, out, nullptr, D_, D_, D_INNER, x, 0);
}

// Round 9
// 267.376 us; speedup vs baseline: 3.9364x; 1.0402x over previous
//
#include <hip/hip_runtime.h>
#include <math.h>

// Problem constants
#define B_ 2
#define L_ 1024
#define D_ 1024
#define D_INNER 2048
#define DT_RANK 64
#define N_STATE 16
#define NC 32          // scan chunks
#define LC 32          // L_/NC

typedef __attribute__((ext_vector_type(8))) short bf16x8;
typedef __attribute__((ext_vector_type(4))) float f32x4;

// ---- bf16 helpers (bit-level, RNE) ----
__device__ __forceinline__ unsigned short f2bf(float f) {
  unsigned int u = __float_as_uint(f);
  u += 0x7fffu + ((u >> 16) & 1u);
  return (unsigned short)(u >> 16);
}
__device__ __forceinline__ float bf2f(unsigned short s) {
  return __uint_as_float((unsigned int)s << 16);
}
__device__ __forceinline__ float softplus_f(float v) {
  return (v > 20.0f) ? v : log1pf(__expf(v));
}

// ---------------- LayerNorm -> bf16 ----------------
__global__ __launch_bounds__(256) void ln_kernel(const float* __restrict__ x,
                                                 const float* __restrict__ w,
                                                 const float* __restrict__ b,
                                                 unsigned short* __restrict__ out) {
  int row = blockIdx.x;
  int tid = threadIdx.x;
  const float* xr = x + (size_t)row * D_;
  float4 v = ((const float4*)xr)[tid];
  float s  = v.x + v.y + v.z + v.w;
  float s2 = v.x*v.x + v.y*v.y + v.z*v.z + v.w*v.w;
  #pragma unroll
  for (int off = 32; off > 0; off >>= 1) {
    s  += __shfl_down(s, off);
    s2 += __shfl_down(s2, off);
  }
  __shared__ float ss[4], ss2[4];
  int wid = tid >> 6, lane = tid & 63;
  if (lane == 0) { ss[wid] = s; ss2[wid] = s2; }
  __syncthreads();
  if (tid == 0) {
    float a  = ss[0] + ss[1] + ss[2] + ss[3];
    float a2 = ss2[0] + ss2[1] + ss2[2] + ss2[3];
    ss[0]  = a  * (1.0f / D_);
    ss2[0] = a2 * (1.0f / D_);
  }
  __syncthreads();
  float mu = ss[0];
  float var = ss2[0] - mu * mu;
  float rstd = rsqrtf(var + 1e-5f);
  float4 wv = ((const float4*)w)[tid];
  float4 bv = ((const float4*)b)[tid];
  ushort4 o;
  o.x = f2bf((v.x - mu) * rstd * wv.x + bv.x);
  o.y = f2bf((v.y - mu) * rstd * wv.y + bv.y);
  o.z = f2bf((v.z - mu) * rstd * wv.z + bv.z);
  o.w = f2bf((v.w - mu) * rstd * wv.w + bv.w);
  ((ushort4*)(out + (size_t)row * D_))[tid] = o;
}

// ---------------- fp32 -> bf16 weight convert ----------------
__global__ __launch_bounds__(256) void cvt_bf16_kernel(const float* __restrict__ in,
                                                       unsigned short* __restrict__ out,
                                                       int n4) {
  int i = blockIdx.x * 256 + threadIdx.x;
  if (i >= n4) return;
  float4 v = ((const float4*)in)[i];
  ushort4 o; o.x = f2bf(v.x); o.y = f2bf(v.y); o.z = f2bf(v.z); o.w = f2bf(v.w);
  ((ushort4*)out)[i] = o;
}

// convert W_xproj [96][2048] -> bf16 padded [128][2048] (rows>=96 zero)
__global__ __launch_bounds__(256) void cvt_wxp_kernel(const float* __restrict__ in,
                                                      unsigned short* __restrict__ out) {
  int i = blockIdx.x * 256 + threadIdx.x;
  int row = (i * 4) >> 11;
  ushort4 o = make_ushort4(0, 0, 0, 0);
  if (row < 96) {
    float4 v = ((const float4*)in)[i];
    o.x = f2bf(v.x); o.y = f2bf(v.y); o.z = f2bf(v.z); o.w = f2bf(v.w);
  }
  ((ushort4*)out)[i] = o;
}

// ---------------- bf16 MFMA GEMM: C[M][N] = A[M][K] * B[N][K]^T ----------------
// BMT x 128 tile, 256 thr (4 waves 2x2), BK=64, global_load_lds(16B) staging,
// st-style XOR swizzle (linear LDS dest + inverse-swizzled global source + swizzled read).
// EPI: 2 = fp32 C + ep0 residual; 3 = xz split (c<2048 -> Cf fp32, else Cb bf16);
//      4 = split-K partial (grid.z slices K/16, out to Cf + z*zstride);
//      5 = fp32 C = softplus(v + ep0[c])   (delta path)
template<int EPI, int BMT>
__global__ __launch_bounds__(256) void gemm_mfma(const unsigned short* __restrict__ A, int lda,
                                                 const unsigned short* __restrict__ B, int ldb,
                                                 float* __restrict__ Cf,
                                                 unsigned short* __restrict__ Cb,
                                                 int ldc, int Nguard, int K,
                                                 const float* __restrict__ ep0,
                                                 size_t zstride = 0) {
  __shared__ unsigned short As[BMT * 64];
  __shared__ unsigned short Bs[128 * 64];
  const int tid = threadIdx.x;
  const int lane = tid & 63;
  const int w = tid >> 6;
  const int wr = w >> 1, wc = w & 1;
  const int bm = blockIdx.y * BMT;
  const int bn = blockIdx.x * 128;
  const int l16 = lane & 15;
  constexpr int MW = BMT / 32;           // M-frags per wave

  int kbeg = 0, kend = K;
  if (EPI == 4) {
    int ks = K >> 4;
    kbeg = blockIdx.z * ks;
    kend = kbeg + ks;
    Cf += (size_t)blockIdx.z * zstride;
  }

  f32x4 acc[MW][4];
  #pragma unroll
  for (int m = 0; m < MW; ++m)
    #pragma unroll
    for (int n = 0; n < 4; ++n) acc[m][n] = (f32x4){0.f, 0.f, 0.f, 0.f};

  for (int k0 = kbeg; k0 < kend; k0 += 64) {
    // stage A tile: linear LDS dest, inverse-swizzled global column
    #pragma unroll
    for (int i = 0; i < BMT / 32; ++i) {
      int p = (i * 256 + tid) * 16;        // linear byte offset in tile
      int r = p >> 7;                      // 128 B per row
      int s = (p >> 4) & 7;                // 16B slot in row
      int cb = ((s ^ (r & 7)) << 3);       // swizzled source element col
      const unsigned short* ga = A + (size_t)(bm + r) * lda + k0 + cb;
      __builtin_amdgcn_global_load_lds(
          (const __attribute__((address_space(1))) void*)ga,
          (__attribute__((address_space(3))) void*)(As + (p >> 1)), 16, 0, 0);
    }
    #pragma unroll
    for (int i = 0; i < 4; ++i) {
      int p = (i * 256 + tid) * 16;
      int r = p >> 7;
      int s = (p >> 4) & 7;
      int cb = ((s ^ (r & 7)) << 3);
      const unsigned short* gb = B + (size_t)(bn + r) * ldb + k0 + cb;
      __builtin_amdgcn_global_load_lds(
          (const __attribute__((address_space(1))) void*)gb,
          (__attribute__((address_space(3))) void*)(Bs + (p >> 1)), 16, 0, 0);
    }
    __syncthreads();
    #pragma unroll
    for (int ks = 0; ks < 2; ++ks) {
      const int slot = ks * 4 + (lane >> 4);
      bf16x8 af[MW], bfr[4];
      #pragma unroll
      for (int m = 0; m < MW; ++m) {
        int ar = wr * (BMT / 2) + m * 16 + l16;
        af[m] = *(const bf16x8*)(As + ar * 64 + ((slot ^ (ar & 7)) << 3));
      }
      #pragma unroll
      for (int n = 0; n < 4; ++n) {
        int br = wc * 64 + n * 16 + l16;
        bfr[n] = *(const bf16x8*)(Bs + br * 64 + ((slot ^ (br & 7)) << 3));
      }
      #pragma unroll
      for (int m = 0; m < MW; ++m)
        #pragma unroll
        for (int n = 0; n < 4; ++n)
          acc[m][n] = __builtin_amdgcn_mfma_f32_16x16x32_bf16(af[m], bfr[n], acc[m][n], 0, 0, 0);
    }
    __syncthreads();
  }

  // epilogue: C row = (lane>>4)*4 + reg, col = lane&15 per fragment
  const int crow0 = bm + wr * (BMT / 2) + (lane >> 4) * 4;
  const int ccol0 = bn + wc * 64 + l16;
  #pragma unroll
  for (int m = 0; m < MW; ++m) {
    #pragma unroll
    for (int n = 0; n < 4; ++n) {
      int c = ccol0 + n * 16;
      if (c >= Nguard) continue;
      #pragma unroll
      for (int r = 0; r < 4; ++r) {
        int rr = crow0 + m * 16 + r;
        float v = acc[m][n][r];
        if (EPI == 2) {
          Cf[(size_t)rr * ldc + c] = v + ep0[(size_t)rr * ldc + c];
        } else if (EPI == 3) {
          if (c < D_INNER) Cf[(size_t)rr * D_INNER + c] = v;
          else             Cb[(size_t)rr * D_INNER + (c - D_INNER)] = f2bf(v);
        } else if (EPI == 5) {
          Cf[(size_t)rr * ldc + c] = softplus_f(v + ep0[c]);
        } else {
          Cf[(size_t)rr * ldc + c] = v;
        }
      }
    }
  }
}

// ---------------- split-K reduce for dbl (+ bf16 dt_low extract) ----------------
__global__ __launch_bounds__(256) void reduce_dbl_kernel(const float* __restrict__ part,
                                                         float* __restrict__ dblb,
                                                         unsigned short* __restrict__ dtlow_b) {
  int i = blockIdx.x * 256 + threadIdx.x;    // 49152 float4s
  float4 a = ((const float4*)part)[i];
  #pragma unroll
  for (int s = 1; s < 16; ++s) {
    float4 b = ((const float4*)part)[s * 49152 + i];
    a.x += b.x; a.y += b.y; a.z += b.z; a.w += b.w;
  }
  ((float4*)dblb)[i] = a;
  int flat = i * 4;
  int row = flat / 96;
  int col = flat - row * 96;
  if (col < 64) {
    ushort4 o; o.x = f2bf(a.x); o.y = f2bf(a.y); o.z = f2bf(a.z); o.w = f2bf(a.w);
    *(ushort4*)(dtlow_b + (size_t)row * 64 + col) = o;
  }
}

// ---------------- Conv1d (depthwise, K=4, causal) + SiLU ----------------
__global__ __launch_bounds__(256) void conv_silu_kernel(const float* __restrict__ xs,
                                                        const float* __restrict__ Wc,
                                                        const float* __restrict__ bc,
                                                        float* __restrict__ xc,
                                                        unsigned short* __restrict__ xcb) {
  int idx = blockIdx.x * 256 + threadIdx.x;
  int e = idx & (D_INNER - 1);
  int t = (idx >> 11) & (L_ - 1);
  float acc = bc[e];
  float w0 = Wc[e * 4 + 0], w1 = Wc[e * 4 + 1], w2 = Wc[e * 4 + 2], w3 = Wc[e * 4 + 3];
  const float* base = xs + (size_t)idx;   // == ((b*L_+t)*D_INNER + e)
  if (t >= 3) acc = fmaf(base[-3 * D_INNER], w0, acc);
  if (t >= 2) acc = fmaf(base[-2 * D_INNER], w1, acc);
  if (t >= 1) acc = fmaf(base[-1 * D_INNER], w2, acc);
  acc = fmaf(base[0], w3, acc);
  float s = acc / (1.0f + __expf(-acc));
  xc[idx] = s;
  xcb[idx] = f2bf(s);
}

// ---------------- Scan phase 1: per-chunk (prod dA, local state) ----------------
__global__ __launch_bounds__(256) void scan1_kernel(const float* __restrict__ delta,
                                                    const float* __restrict__ xc,
                                                    const float* __restrict__ dbl,
                                                    const float* __restrict__ A_log,
                                                    float* __restrict__ P,
                                                    float* __restrict__ Q) {
  int e = blockIdx.x * 256 + threadIdx.x;
  int b = blockIdx.y, c = blockIdx.z;
  const int t0 = (int)(b * L_ + c * LC);

  __shared__ float sB[LC][N_STATE];     // 2 KB
  for (int i = threadIdx.x; i < LC * N_STATE; i += 256) {
    int step = i >> 4, n = i & 15;
    sB[step][n] = dbl[(size_t)(t0 + step) * 96 + 64 + n];
  }
  __syncthreads();

  float An[N_STATE];
  #pragma unroll
  for (int q = 0; q < 4; ++q) {
    float4 v = *(const float4*)&A_log[(size_t)e * N_STATE + q * 4];
    An[q*4+0] = -__expf(v.x); An[q*4+1] = -__expf(v.y);
    An[q*4+2] = -__expf(v.z); An[q*4+3] = -__expf(v.w);
  }
  float h[N_STATE], p[N_STATE];
  #pragma unroll
  for (int n = 0; n < N_STATE; ++n) { h[n] = 0.f; p[n] = 1.f; }

  const size_t row0 = (size_t)t0 * D_INNER + e;
  float dlt = delta[row0];
  float xcv = xc[row0];

  for (int tt = 0; tt < LC; ++tt) {
    float ndlt = 0.f, nxcv = 0.f;
    if (tt + 1 < LC) {
      ndlt = delta[row0 + (size_t)(tt + 1) * D_INNER];
      nxcv = xc[row0 + (size_t)(tt + 1) * D_INNER];
    }
    float dbx = dlt * xcv;
    #pragma unroll
    for (int n = 0; n < N_STATE; ++n) {
      float da = __expf(dlt * An[n]);
      h[n] = fmaf(da, h[n], dbx * sB[tt][n]);
      p[n] *= da;
    }
    dlt = ndlt; xcv = nxcv;
  }
  size_t o = ((size_t)(c * B_ + b) * N_STATE) * D_INNER + e;
  #pragma unroll
  for (int n = 0; n < N_STATE; ++n) {
    P[o + (size_t)n * D_INNER] = p[n];
    Q[o + (size_t)n * D_INNER] = h[n];
  }
}

// ---------------- Scan phase 2: combine chunk states (Hinit in-place in Q) ----
__global__ __launch_bounds__(256) void scan2_kernel(const float* __restrict__ P,
                                                    float* __restrict__ Q) {
  int idx = blockIdx.x * 256 + threadIdx.x;  // B_*N_STATE*D_INNER = 65536
  float H = 0.f;
  #pragma unroll
  for (int c = 0; c < NC; ++c) {
    size_t o = (size_t)c * (B_ * N_STATE * D_INNER) + idx;
    float p = P[o], q = Q[o];
    Q[o] = H;                         // Hinit for chunk c
    H = fmaf(p, H, q);
  }
}

// ---------------- Scan phase 3: replay + fused gate -> y (bf16) ----------------
__global__ __launch_bounds__(256) void scan3_kernel(const float* __restrict__ delta,
                                                    const float* __restrict__ xc,
                                                    const float* __restrict__ dbl,
                                                    const float* __restrict__ A_log,
                                                    const float* __restrict__ Hinit,
                                                    const unsigned short* __restrict__ zb,
                                                    const float* __restrict__ Dsk,
                                                    unsigned short* __restrict__ y) {
  int e = blockIdx.x * 256 + threadIdx.x;
  int b = blockIdx.y, c = blockIdx.z;
  const int t0 = (int)(b * L_ + c * LC);

  __shared__ float sB[LC][N_STATE];     // 2 KB
  __shared__ float sC[LC][N_STATE];     // 2 KB
  for (int i = threadIdx.x; i < LC * N_STATE; i += 256) {
    int step = i >> 4, n = i & 15;
    const float* row = dbl + (size_t)(t0 + step) * 96;
    sB[step][n] = row[64 + n];
    sC[step][n] = row[80 + n];
  }
  __syncthreads();

  float An[N_STATE];
  #pragma unroll
  for (int q = 0; q < 4; ++q) {
    float4 v = *(const float4*)&A_log[(size_t)e * N_STATE + q * 4];
    An[q*4+0] = -__expf(v.x); An[q*4+1] = -__expf(v.y);
    An[q*4+2] = -__expf(v.z); An[q*4+3] = -__expf(v.w);
  }
  float h[N_STATE];
  {
    size_t o = (size_t)c * (B_ * N_STATE * D_INNER) + (size_t)b * (N_STATE * D_INNER) + e;
    #pragma unroll
    for (int n = 0; n < N_STATE; ++n) h[n] = Hinit[o + (size_t)n * D_INNER];
  }
  float dskip = Dsk[e];
  const size_t row0 = (size_t)t0 * D_INNER + e;

  float dlt = delta[row0];
  float xcv = xc[row0];
  float zv  = bf2f(zb[row0]);

  for (int tt = 0; tt < LC; ++tt) {
    float ndlt = 0.f, nxcv = 0.f, nzv = 0.f;
    if (tt + 1 < LC) {
      ndlt = delta[row0 + (size_t)(tt + 1) * D_INNER];
      nxcv = xc[row0 + (size_t)(tt + 1) * D_INNER];
      nzv  = bf2f(zb[row0 + (size_t)(tt + 1) * D_INNER]);
    }
    float dbx = dlt * xcv;
    float yv = 0.f;
    #pragma unroll
    for (int n = 0; n < N_STATE; ++n) {
      float da = __expf(dlt * An[n]);
      h[n] = fmaf(da, h[n], dbx * sB[tt][n]);
      yv = fmaf(h[n], sC[tt][n], yv);
    }
    float gate = zv / (1.0f + __expf(-zv));
    y[row0 + (size_t)tt * D_INNER] = f2bf((yv + dskip * xcv) * gate);
    dlt = ndlt; xcv = nxcv; zv = nzv;
  }
}

// ---------------- launch ----------------
extern "C" void kernel_launch(void* const* d_in, const int* in_sizes, int n_in,
                              void* d_out, int out_size, void* d_ws, size_t ws_size,
                              hipStream_t stream) {
  const float* x       = (const float*)d_in[0];
  const float* ln_w    = (const float*)d_in[1];
  const float* ln_b    = (const float*)d_in[2];
  const float* W_in    = (const float*)d_in[3];
  const float* W_conv  = (const float*)d_in[4];
  const float* b_conv  = (const float*)d_in[5];
  const float* W_xproj = (const float*)d_in[6];
  const float* W_dt    = (const float*)d_in[7];
  const float* b_dt    = (const float*)d_in[8];
  const float* A_log   = (const float*)d_in[9];
  const float* D_skip  = (const float*)d_in[10];
  const float* W_out   = (const float*)d_in[11];
  float* out = (float*)d_out;
  float* ws  = (float*)d_ws;

  const size_t BL = (size_t)B_ * L_;            // 2048
  // fp32 region (12,779,520 floats = 51.1 MB)
  float* xs    = ws;                            // 4,194,304
  float* xc    = xs    + BL * D_INNER;          // 4,194,304
  float* delta = xc    + BL * D_INNER;          // 4,194,304
  float* dblb  = delta + BL * D_INNER;          // 196,608
  // bf16 region (21,495,808 shorts = 43.0 MB; region start is 16B-aligned)
  unsigned short* xn_b   = (unsigned short*)(dblb + BL * 96);
  unsigned short* Win_b  = xn_b   + 2097152;    // 4096*1024
  unsigned short* z_b    = Win_b  + 4194304;    // 2048*2048
  unsigned short* xc_b   = z_b    + 4194304;    // 2048*2048
  unsigned short* Wxp_b  = xc_b   + 4194304;    // 128*2048 (padded)
  unsigned short* y_b    = Wxp_b  + 262144;     // 2048*2048
  unsigned short* Wout_b = y_b    + 4194304;    // 1024*2048
  unsigned short* dtlow_b= Wout_b + 2097152;    // 2048*64
  unsigned short* Wdt_b  = dtlow_b+ 131072;     // 2048*64
  // Aliases (all dead at use time):
  // P (2,097,152 f) over xn_b + first half of Win_b (dead after input GEMM)
  // Q (2,097,152 f) over xc_b exactly (dead after dbl GEMM); Hinit in-place in Q
  // part (3,145,728 f = 16 x 2048 x 96) over y_b + Wout_b (dead until scan3 / re-cvt)
  float* P    = (float*)xn_b;
  float* Q    = (float*)xc_b;
  float* part = (float*)y_b;

  // 1. LayerNorm -> xn_b
  ln_kernel<<<BL, 256, 0, stream>>>(x, ln_w, ln_b, xn_b);
  // 2. weight converts (W_out converted later, after dbl partials are dead)
  cvt_bf16_kernel<<<4096, 256, 0, stream>>>(W_in, Win_b, 1048576);
  cvt_wxp_kernel<<<256, 256, 0, stream>>>(W_xproj, Wxp_b);
  cvt_bf16_kernel<<<128, 256, 0, stream>>>(W_dt, Wdt_b, 32768);
  // 3. merged input GEMM: [xs | z] = xn @ W_in^T  (M=2048, N=4096, K=1024)
  gemm_mfma<3, 128><<<dim3(32, 16), 256, 0, stream>>>(
      xn_b, D_, Win_b, D_, xs, z_b, D_INNER, 4096, D_, nullptr, 0);
  // 4. conv + silu -> xc (fp32) + xc_b (bf16)
  conv_silu_kernel<<<(BL * D_INNER) / 256, 256, 0, stream>>>(xs, W_conv, b_conv, xc, xc_b);
  // 5. dbl = xc @ W_xproj^T  split-K x16 partials (N=96 padded to 128)
  gemm_mfma<4, 128><<<dim3(1, 16, 16), 256, 0, stream>>>(
      xc_b, D_INNER, Wxp_b, D_INNER, part, nullptr, 96, 96, D_INNER, nullptr,
      (size_t)2048 * 96);
  reduce_dbl_kernel<<<192, 256, 0, stream>>>(part, dblb, dtlow_b);
  // 6. now safe: convert W_out (overwrites former partial region)
  cvt_bf16_kernel<<<2048, 256, 0, stream>>>(W_out, Wout_b, 524288);
  // 7. delta = softplus(dt_low @ W_dt^T + b_dt) via MFMA (M=2048, N=2048, K=64)
  gemm_mfma<5, 128><<<dim3(16, 16), 256, 0, stream>>>(
      dtlow_b, DT_RANK, Wdt_b, DT_RANK, delta, nullptr, D_INNER, D_INNER, DT_RANK, b_dt, 0);
  // 8. chunked scan (NC=32)
  scan1_kernel<<<dim3(D_INNER / 256, B_, NC), 256, 0, stream>>>(delta, xc, dblb, A_log, P, Q);
  scan2_kernel<<<(B_ * N_STATE * D_INNER) / 256, 256, 0, stream>>>(P, Q);
  scan3_kernel<<<dim3(D_INNER / 256, B_, NC), 256, 0, stream>>>(delta, xc, dblb, A_log, Q,
                                                                z_b, D_skip, y_b);
  // 9. out = y @ W_out^T + residual  (64x128 tile -> 256 blocks)
  gemm_mfma<2, 64><<<dim3(8, 32), 256, 0, stream>>>(
      y_b, D_INNER, Wout_b, D_INNER, out, nullptr, D_, D_, D_INNER, x, 0);
}

// Round 10
// 260.230 us; speedup vs baseline: 4.0445x; 1.0275x over previous
//
#include <hip/hip_runtime.h>
#include <math.h>

// Problem constants
#define B_ 2
#define L_ 1024
#define D_ 1024
#define D_INNER 2048
#define DT_RANK 64
#define N_STATE 16
#define NC 64          // scan chunks
#define LC 16          // L_/NC

typedef __attribute__((ext_vector_type(8))) short bf16x8;
typedef __attribute__((ext_vector_type(4))) float f32x4;

// ---- bf16 helpers (bit-level, RNE) ----
__device__ __forceinline__ unsigned short f2bf(float f) {
  unsigned int u = __float_as_uint(f);
  u += 0x7fffu + ((u >> 16) & 1u);
  return (unsigned short)(u >> 16);
}
__device__ __forceinline__ float bf2f(unsigned short s) {
  return __uint_as_float((unsigned int)s << 16);
}
__device__ __forceinline__ float softplus_f(float v) {
  return (v > 20.0f) ? v : log1pf(__expf(v));
}

// ---------------- LayerNorm -> bf16 ----------------
__global__ __launch_bounds__(256) void ln_kernel(const float* __restrict__ x,
                                                 const float* __restrict__ w,
                                                 const float* __restrict__ b,
                                                 unsigned short* __restrict__ out) {
  int row = blockIdx.x;
  int tid = threadIdx.x;
  const float* xr = x + (size_t)row * D_;
  float4 v = ((const float4*)xr)[tid];
  float s  = v.x + v.y + v.z + v.w;
  float s2 = v.x*v.x + v.y*v.y + v.z*v.z + v.w*v.w;
  #pragma unroll
  for (int off = 32; off > 0; off >>= 1) {
    s  += __shfl_down(s, off);
    s2 += __shfl_down(s2, off);
  }
  __shared__ float ss[4], ss2[4];
  int wid = tid >> 6, lane = tid & 63;
  if (lane == 0) { ss[wid] = s; ss2[wid] = s2; }
  __syncthreads();
  if (tid == 0) {
    float a  = ss[0] + ss[1] + ss[2] + ss[3];
    float a2 = ss2[0] + ss2[1] + ss2[2] + ss2[3];
    ss[0]  = a  * (1.0f / D_);
    ss2[0] = a2 * (1.0f / D_);
  }
  __syncthreads();
  float mu = ss[0];
  float var = ss2[0] - mu * mu;
  float rstd = rsqrtf(var + 1e-5f);
  float4 wv = ((const float4*)w)[tid];
  float4 bv = ((const float4*)b)[tid];
  ushort4 o;
  o.x = f2bf((v.x - mu) * rstd * wv.x + bv.x);
  o.y = f2bf((v.y - mu) * rstd * wv.y + bv.y);
  o.z = f2bf((v.z - mu) * rstd * wv.z + bv.z);
  o.w = f2bf((v.w - mu) * rstd * wv.w + bv.w);
  ((ushort4*)(out + (size_t)row * D_))[tid] = o;
}

// ---------------- fused weight converts (W_in | W_out | W_dt | W_xproj-pad) ----
#define N4_WIN  1048576   // 4096*1024/4
#define N4_WOUT  524288   // 1024*2048/4
#define N4_WDT    32768   // 2048*64/4
#define N4_WXP    65536   // 128*2048/4 (padded out)
__global__ __launch_bounds__(256) void cvt_all_kernel(const float* __restrict__ W_in,
                                                      const float* __restrict__ W_out,
                                                      const float* __restrict__ W_dt,
                                                      const float* __restrict__ W_xp,
                                                      unsigned short* __restrict__ Win_b,
                                                      unsigned short* __restrict__ Wout_b,
                                                      unsigned short* __restrict__ Wdt_b,
                                                      unsigned short* __restrict__ Wxp_b) {
  int i = blockIdx.x * 256 + threadIdx.x;
  if (i < N4_WIN) {
    float4 v = ((const float4*)W_in)[i];
    ushort4 o; o.x = f2bf(v.x); o.y = f2bf(v.y); o.z = f2bf(v.z); o.w = f2bf(v.w);
    ((ushort4*)Win_b)[i] = o;
    return;
  }
  i -= N4_WIN;
  if (i < N4_WOUT) {
    float4 v = ((const float4*)W_out)[i];
    ushort4 o; o.x = f2bf(v.x); o.y = f2bf(v.y); o.z = f2bf(v.z); o.w = f2bf(v.w);
    ((ushort4*)Wout_b)[i] = o;
    return;
  }
  i -= N4_WOUT;
  if (i < N4_WDT) {
    float4 v = ((const float4*)W_dt)[i];
    ushort4 o; o.x = f2bf(v.x); o.y = f2bf(v.y); o.z = f2bf(v.z); o.w = f2bf(v.w);
    ((ushort4*)Wdt_b)[i] = o;
    return;
  }
  i -= N4_WDT;
  if (i < N4_WXP) {
    int row = (i * 4) >> 11;
    ushort4 o = make_ushort4(0, 0, 0, 0);
    if (row < 96) {
      float4 v = ((const float4*)W_xp)[i];
      o.x = f2bf(v.x); o.y = f2bf(v.y); o.z = f2bf(v.z); o.w = f2bf(v.w);
    }
    ((ushort4*)Wxp_b)[i] = o;
  }
}

// ---------------- bf16 MFMA GEMM: C[M][N] = A[M][K] * B[N][K]^T ----------------
// BMT x 128 tile, 256 thr (4 waves 2x2), BK=64, global_load_lds(16B) staging,
// st-style XOR swizzle (linear LDS dest + inverse-swizzled global source + swizzled read).
// EPI: 1 = bf16 C; 2 = fp32 C + ep0 residual;
//      4 = split-K partial (grid.z slices K/16, out to Cf + z*zstride);
//      5 = bf16 C = softplus(v + ep0[c])   (delta path)
template<int EPI, int BMT>
__global__ __launch_bounds__(256) void gemm_mfma(const unsigned short* __restrict__ A, int lda,
                                                 const unsigned short* __restrict__ B, int ldb,
                                                 float* __restrict__ Cf,
                                                 unsigned short* __restrict__ Cb,
                                                 int ldc, int Nguard, int K,
                                                 const float* __restrict__ ep0,
                                                 size_t zstride = 0) {
  __shared__ unsigned short As[BMT * 64];
  __shared__ unsigned short Bs[128 * 64];
  const int tid = threadIdx.x;
  const int lane = tid & 63;
  const int w = tid >> 6;
  const int wr = w >> 1, wc = w & 1;
  const int bm = blockIdx.y * BMT;
  const int bn = blockIdx.x * 128;
  const int l16 = lane & 15;
  constexpr int MW = BMT / 32;           // M-frags per wave

  int kbeg = 0, kend = K;
  if (EPI == 4) {
    int ks = K >> 4;
    kbeg = blockIdx.z * ks;
    kend = kbeg + ks;
    Cf += (size_t)blockIdx.z * zstride;
  }

  f32x4 acc[MW][4];
  #pragma unroll
  for (int m = 0; m < MW; ++m)
    #pragma unroll
    for (int n = 0; n < 4; ++n) acc[m][n] = (f32x4){0.f, 0.f, 0.f, 0.f};

  for (int k0 = kbeg; k0 < kend; k0 += 64) {
    // stage A tile: linear LDS dest, inverse-swizzled global column
    #pragma unroll
    for (int i = 0; i < BMT / 32; ++i) {
      int p = (i * 256 + tid) * 16;        // linear byte offset in tile
      int r = p >> 7;                      // 128 B per row
      int s = (p >> 4) & 7;                // 16B slot in row
      int cb = ((s ^ (r & 7)) << 3);       // swizzled source element col
      const unsigned short* ga = A + (size_t)(bm + r) * lda + k0 + cb;
      __builtin_amdgcn_global_load_lds(
          (const __attribute__((address_space(1))) void*)ga,
          (__attribute__((address_space(3))) void*)(As + (p >> 1)), 16, 0, 0);
    }
    #pragma unroll
    for (int i = 0; i < 4; ++i) {
      int p = (i * 256 + tid) * 16;
      int r = p >> 7;
      int s = (p >> 4) & 7;
      int cb = ((s ^ (r & 7)) << 3);
      const unsigned short* gb = B + (size_t)(bn + r) * ldb + k0 + cb;
      __builtin_amdgcn_global_load_lds(
          (const __attribute__((address_space(1))) void*)gb,
          (__attribute__((address_space(3))) void*)(Bs + (p >> 1)), 16, 0, 0);
    }
    __syncthreads();
    #pragma unroll
    for (int ks = 0; ks < 2; ++ks) {
      const int slot = ks * 4 + (lane >> 4);
      bf16x8 af[MW], bfr[4];
      #pragma unroll
      for (int m = 0; m < MW; ++m) {
        int ar = wr * (BMT / 2) + m * 16 + l16;
        af[m] = *(const bf16x8*)(As + ar * 64 + ((slot ^ (ar & 7)) << 3));
      }
      #pragma unroll
      for (int n = 0; n < 4; ++n) {
        int br = wc * 64 + n * 16 + l16;
        bfr[n] = *(const bf16x8*)(Bs + br * 64 + ((slot ^ (br & 7)) << 3));
      }
      #pragma unroll
      for (int m = 0; m < MW; ++m)
        #pragma unroll
        for (int n = 0; n < 4; ++n)
          acc[m][n] = __builtin_amdgcn_mfma_f32_16x16x32_bf16(af[m], bfr[n], acc[m][n], 0, 0, 0);
    }
    __syncthreads();
  }

  // epilogue: C row = (lane>>4)*4 + reg, col = lane&15 per fragment
  const int crow0 = bm + wr * (BMT / 2) + (lane >> 4) * 4;
  const int ccol0 = bn + wc * 64 + l16;
  #pragma unroll
  for (int m = 0; m < MW; ++m) {
    #pragma unroll
    for (int n = 0; n < 4; ++n) {
      int c = ccol0 + n * 16;
      if (c >= Nguard) continue;
      #pragma unroll
      for (int r = 0; r < 4; ++r) {
        int rr = crow0 + m * 16 + r;
        float v = acc[m][n][r];
        if (EPI == 1) {
          Cb[(size_t)rr * ldc + c] = f2bf(v);
        } else if (EPI == 2) {
          Cf[(size_t)rr * ldc + c] = v + ep0[(size_t)rr * ldc + c];
        } else if (EPI == 5) {
          Cb[(size_t)rr * ldc + c] = f2bf(softplus_f(v + ep0[c]));
        } else {
          Cf[(size_t)rr * ldc + c] = v;
        }
      }
    }
  }
}

// ---------------- split-K reduce for dbl (+ bf16 dt_low extract) ----------------
__global__ __launch_bounds__(256) void reduce_dbl_kernel(const float* __restrict__ part,
                                                         float* __restrict__ dblb,
                                                         unsigned short* __restrict__ dtlow_b) {
  int i = blockIdx.x * 256 + threadIdx.x;    // 49152 float4s
  float4 a = ((const float4*)part)[i];
  #pragma unroll
  for (int s = 1; s < 16; ++s) {
    float4 b = ((const float4*)part)[s * 49152 + i];
    a.x += b.x; a.y += b.y; a.z += b.z; a.w += b.w;
  }
  ((float4*)dblb)[i] = a;
  int flat = i * 4;
  int row = flat / 96;
  int col = flat - row * 96;
  if (col < 64) {
    ushort4 o; o.x = f2bf(a.x); o.y = f2bf(a.y); o.z = f2bf(a.z); o.w = f2bf(a.w);
    *(ushort4*)(dtlow_b + (size_t)row * 64 + col) = o;
  }
}

// ---------------- Conv1d (depthwise, K=4, causal) + SiLU, bf16 in/out --------
__global__ __launch_bounds__(256) void conv_silu_kernel(const unsigned short* __restrict__ xz,
                                                        const float* __restrict__ Wc,
                                                        const float* __restrict__ bc,
                                                        unsigned short* __restrict__ xcb) {
  int idx = blockIdx.x * 256 + threadIdx.x;   // (b*L+t)*D_INNER + e
  int e = idx & (D_INNER - 1);
  int t = (idx >> 11) & (L_ - 1);
  int bt = idx >> 11;                         // b*L + t
  float acc = bc[e];
  float w0 = Wc[e * 4 + 0], w1 = Wc[e * 4 + 1], w2 = Wc[e * 4 + 2], w3 = Wc[e * 4 + 3];
  const unsigned short* base = xz + (size_t)bt * 4096 + e;   // xs half of xz row
  if (t >= 3) acc = fmaf(bf2f(base[-3 * 4096]), w0, acc);
  if (t >= 2) acc = fmaf(bf2f(base[-2 * 4096]), w1, acc);
  if (t >= 1) acc = fmaf(bf2f(base[-1 * 4096]), w2, acc);
  acc = fmaf(bf2f(base[0]), w3, acc);
  float s = acc / (1.0f + __expf(-acc));
  xcb[idx] = f2bf(s);
}

// ---------------- Scan phase 1: per-chunk (prod dA, local state) ----------------
__global__ __launch_bounds__(256) void scan1_kernel(const unsigned short* __restrict__ delta,
                                                    const unsigned short* __restrict__ xc,
                                                    const float* __restrict__ dbl,
                                                    const float* __restrict__ A_log,
                                                    float* __restrict__ P,
                                                    float* __restrict__ Q) {
  int e = blockIdx.x * 256 + threadIdx.x;
  int b = blockIdx.y, c = blockIdx.z;
  const int t0 = (int)(b * L_ + c * LC);

  __shared__ float sB[LC][N_STATE];     // 1 KB
  {
    int step = threadIdx.x >> 4, n = threadIdx.x & 15;
    sB[step][n] = dbl[(size_t)(t0 + step) * 96 + 64 + n];
  }
  __syncthreads();

  float An[N_STATE];
  #pragma unroll
  for (int q = 0; q < 4; ++q) {
    float4 v = *(const float4*)&A_log[(size_t)e * N_STATE + q * 4];
    An[q*4+0] = -__expf(v.x); An[q*4+1] = -__expf(v.y);
    An[q*4+2] = -__expf(v.z); An[q*4+3] = -__expf(v.w);
  }
  float h[N_STATE], p[N_STATE];
  #pragma unroll
  for (int n = 0; n < N_STATE; ++n) { h[n] = 0.f; p[n] = 1.f; }

  const size_t row0 = (size_t)t0 * D_INNER + e;
  float dlt = bf2f(delta[row0]);
  float xcv = bf2f(xc[row0]);

  for (int tt = 0; tt < LC; ++tt) {
    float ndlt = 0.f, nxcv = 0.f;
    if (tt + 1 < LC) {
      ndlt = bf2f(delta[row0 + (size_t)(tt + 1) * D_INNER]);
      nxcv = bf2f(xc[row0 + (size_t)(tt + 1) * D_INNER]);
    }
    float dbx = dlt * xcv;
    #pragma unroll
    for (int n = 0; n < N_STATE; ++n) {
      float da = __expf(dlt * An[n]);
      h[n] = fmaf(da, h[n], dbx * sB[tt][n]);
      p[n] *= da;
    }
    dlt = ndlt; xcv = nxcv;
  }
  size_t o = ((size_t)(c * B_ + b) * N_STATE) * D_INNER + e;
  #pragma unroll
  for (int n = 0; n < N_STATE; ++n) {
    P[o + (size_t)n * D_INNER] = p[n];
    Q[o + (size_t)n * D_INNER] = h[n];
  }
}

// ---------------- Scan phase 2: combine chunk states (Hinit in-place in Q) ----
__global__ __launch_bounds__(256) void scan2_kernel(const float* __restrict__ P,
                                                    float* __restrict__ Q) {
  int idx = blockIdx.x * 256 + threadIdx.x;  // B_*N_STATE*D_INNER = 65536
  float H = 0.f;
  #pragma unroll
  for (int c = 0; c < NC; ++c) {
    size_t o = (size_t)c * (B_ * N_STATE * D_INNER) + idx;
    float p = P[o], q = Q[o];
    Q[o] = H;                         // Hinit for chunk c
    H = fmaf(p, H, q);
  }
}

// ---------------- Scan phase 3: replay + fused gate -> y (bf16) ----------------
__global__ __launch_bounds__(256) void scan3_kernel(const unsigned short* __restrict__ delta,
                                                    const unsigned short* __restrict__ xc,
                                                    const float* __restrict__ dbl,
                                                    const float* __restrict__ A_log,
                                                    const float* __restrict__ Hinit,
                                                    const unsigned short* __restrict__ xz,
                                                    const float* __restrict__ Dsk,
                                                    unsigned short* __restrict__ y) {
  int e = blockIdx.x * 256 + threadIdx.x;
  int b = blockIdx.y, c = blockIdx.z;
  const int t0 = (int)(b * L_ + c * LC);

  __shared__ float sB[LC][N_STATE];     // 1 KB
  __shared__ float sC[LC][N_STATE];     // 1 KB
  {
    int step = threadIdx.x >> 4, n = threadIdx.x & 15;
    const float* row = dbl + (size_t)(t0 + step) * 96;
    sB[step][n] = row[64 + n];
    sC[step][n] = row[80 + n];
  }
  __syncthreads();

  float An[N_STATE];
  #pragma unroll
  for (int q = 0; q < 4; ++q) {
    float4 v = *(const float4*)&A_log[(size_t)e * N_STATE + q * 4];
    An[q*4+0] = -__expf(v.x); An[q*4+1] = -__expf(v.y);
    An[q*4+2] = -__expf(v.z); An[q*4+3] = -__expf(v.w);
  }
  float h[N_STATE];
  {
    size_t o = ((size_t)(c * B_ + b) * N_STATE) * D_INNER + e;
    #pragma unroll
    for (int n = 0; n < N_STATE; ++n) h[n] = Hinit[o + (size_t)n * D_INNER];
  }
  float dskip = Dsk[e];
  const size_t row0 = (size_t)t0 * D_INNER + e;
  const size_t zrow0 = (size_t)t0 * 4096 + D_INNER + e;

  float dlt = bf2f(delta[row0]);
  float xcv = bf2f(xc[row0]);
  float zv  = bf2f(xz[zrow0]);

  for (int tt = 0; tt < LC; ++tt) {
    float ndlt = 0.f, nxcv = 0.f, nzv = 0.f;
    if (tt + 1 < LC) {
      ndlt = bf2f(delta[row0 + (size_t)(tt + 1) * D_INNER]);
      nxcv = bf2f(xc[row0 + (size_t)(tt + 1) * D_INNER]);
      nzv  = bf2f(xz[zrow0 + (size_t)(tt + 1) * 4096]);
    }
    float dbx = dlt * xcv;
    float yv = 0.f;
    #pragma unroll
    for (int n = 0; n < N_STATE; ++n) {
      float da = __expf(dlt * An[n]);
      h[n] = fmaf(da, h[n], dbx * sB[tt][n]);
      yv = fmaf(h[n], sC[tt][n], yv);
    }
    float gate = zv / (1.0f + __expf(-zv));
    y[row0 + (size_t)tt * D_INNER] = f2bf((yv + dskip * xcv) * gate);
    dlt = ndlt; xcv = nxcv; zv = nzv;
  }
}

// ---------------- launch ----------------
extern "C" void kernel_launch(void* const* d_in, const int* in_sizes, int n_in,
                              void* d_out, int out_size, void* d_ws, size_t ws_size,
                              hipStream_t stream) {
  const float* x       = (const float*)d_in[0];
  const float* ln_w    = (const float*)d_in[1];
  const float* ln_b    = (const float*)d_in[2];
  const float* W_in    = (const float*)d_in[3];
  const float* W_conv  = (const float*)d_in[4];
  const float* b_conv  = (const float*)d_in[5];
  const float* W_xproj = (const float*)d_in[6];
  const float* W_dt    = (const float*)d_in[7];
  const float* b_dt    = (const float*)d_in[8];
  const float* A_log   = (const float*)d_in[9];
  const float* D_skip  = (const float*)d_in[10];
  const float* W_out   = (const float*)d_in[11];
  float* out = (float*)d_out;

  const size_t BL = (size_t)B_ * L_;            // 2048
  // fp32 region (plain linear layout, no aliasing; ws is ~268 MB)
  float* dblb = (float*)d_ws;                   // 196,608 f
  float* part = dblb + 196608;                  // 3,145,728 f (16 x 2048 x 96)
  float* P    = part + 3145728;                 // 4,194,304 f (NC=64)
  float* Q    = P    + 4194304;                 // 4,194,304 f
  // bf16 region
  unsigned short* xn_b    = (unsigned short*)(Q + 4194304);
  unsigned short* Win_b   = xn_b    + 2097152;  // 4096*1024
  unsigned short* xz_b    = Win_b   + 4194304;  // 2048*4096
  unsigned short* xc_b    = xz_b    + 8388608;  // 2048*2048
  unsigned short* Wxp_b   = xc_b    + 4194304;  // 128*2048 (padded)
  unsigned short* y_b     = Wxp_b   + 262144;   // 2048*2048
  unsigned short* Wout_b  = y_b     + 4194304;  // 1024*2048
  unsigned short* dtlow_b = Wout_b  + 2097152;  // 2048*64
  unsigned short* Wdt_b   = dtlow_b + 131072;   // 2048*64
  unsigned short* delta_b = Wdt_b   + 131072;   // 2048*2048

  // 1. LayerNorm -> xn_b
  ln_kernel<<<BL, 256, 0, stream>>>(x, ln_w, ln_b, xn_b);
  // 2. fused weight converts
  cvt_all_kernel<<<(N4_WIN + N4_WOUT + N4_WDT + N4_WXP + 255) / 256, 256, 0, stream>>>(
      W_in, W_out, W_dt, W_xproj, Win_b, Wout_b, Wdt_b, Wxp_b);
  // 3. input GEMM: xz = xn @ W_in^T  (M=2048, N=4096, K=1024), bf16 out
  gemm_mfma<1, 128><<<dim3(32, 16), 256, 0, stream>>>(
      xn_b, D_, Win_b, D_, nullptr, xz_b, 4096, 4096, D_, nullptr, 0);
  // 4. conv + silu -> xc_b (bf16)
  conv_silu_kernel<<<(BL * D_INNER) / 256, 256, 0, stream>>>(xz_b, W_conv, b_conv, xc_b);
  // 5. dbl = xc @ W_xproj^T  split-K x16 partials (N=96 padded to 128)
  gemm_mfma<4, 128><<<dim3(1, 16, 16), 256, 0, stream>>>(
      xc_b, D_INNER, Wxp_b, D_INNER, part, nullptr, 96, 96, D_INNER, nullptr,
      (size_t)2048 * 96);
  reduce_dbl_kernel<<<192, 256, 0, stream>>>(part, dblb, dtlow_b);
  // 6. delta = softplus(dt_low @ W_dt^T + b_dt) via MFMA -> bf16
  gemm_mfma<5, 128><<<dim3(16, 16), 256, 0, stream>>>(
      dtlow_b, DT_RANK, Wdt_b, DT_RANK, nullptr, delta_b, D_INNER, D_INNER, DT_RANK, b_dt, 0);
  // 7. chunked scan (NC=64)
  scan1_kernel<<<dim3(D_INNER / 256, B_, NC), 256, 0, stream>>>(delta_b, xc_b, dblb, A_log, P, Q);
  scan2_kernel<<<(B_ * N_STATE * D_INNER) / 256, 256, 0, stream>>>(P, Q);
  scan3_kernel<<<dim3(D_INNER / 256, B_, NC), 256, 0, stream>>>(delta_b, xc_b, dblb, A_log, Q,
                                                                xz_b, D_skip, y_b);
  // 8. out = y @ W_out^T + residual  (64x128 tile -> 256 blocks)
  gemm_mfma<2, 64><<<dim3(8, 32), 256, 0, stream>>>(
      y_b, D_INNER, Wout_b, D_INNER, out, nullptr, D_, D_, D_INNER, x, 0);
}

// Round 12
// 256.276 us; speedup vs baseline: 4.1069x; 1.0154x over previous
//
#include <hip/hip_runtime.h>
#include <math.h>

// Problem constants
#define B_ 2
#define L_ 1024
#define D_ 1024
#define D_INNER 2048
#define DT_RANK 64
#define N_STATE 16
#define NC 64          // scan chunks
#define LC 16          // L_/NC

typedef __attribute__((ext_vector_type(8))) short bf16x8;
typedef __attribute__((ext_vector_type(4))) float f32x4;

// ---- bf16 helpers (bit-level, RNE) ----
__device__ __forceinline__ unsigned short f2bf(float f) {
  unsigned int u = __float_as_uint(f);
  u += 0x7fffu + ((u >> 16) & 1u);
  return (unsigned short)(u >> 16);
}
__device__ __forceinline__ float bf2f(unsigned short s) {
  return __uint_as_float((unsigned int)s << 16);
}
__device__ __forceinline__ float softplus_f(float v) {
  return (v > 20.0f) ? v : log1pf(__expf(v));
}

// ---------------- prep: LayerNorm (blocks < 2048) + weight converts ----------
#define N4_WIN  1048576   // 4096*1024/4
#define N4_WOUT  524288   // 1024*2048/4
#define N4_WDT    32768   // 2048*64/4
#define N4_WXP    65536   // 128*2048/4 (padded out)
#define CVT_BLOCKS ((N4_WIN + N4_WOUT + N4_WDT + N4_WXP + 255) / 256)

__global__ __launch_bounds__(256) void prep_kernel(const float* __restrict__ x,
                                                   const float* __restrict__ w,
                                                   const float* __restrict__ b,
                                                   unsigned short* __restrict__ xn_b,
                                                   const float* __restrict__ W_in,
                                                   const float* __restrict__ W_out,
                                                   const float* __restrict__ W_dt,
                                                   const float* __restrict__ W_xp,
                                                   unsigned short* __restrict__ Win_b,
                                                   unsigned short* __restrict__ Wout_b,
                                                   unsigned short* __restrict__ Wdt_b,
                                                   unsigned short* __restrict__ Wxp_b) {
  if (blockIdx.x < 2048) {
    int row = blockIdx.x;
    int tid = threadIdx.x;
    const float* xr = x + (size_t)row * D_;
    float4 v = ((const float4*)xr)[tid];
    float s  = v.x + v.y + v.z + v.w;
    float s2 = v.x*v.x + v.y*v.y + v.z*v.z + v.w*v.w;
    #pragma unroll
    for (int off = 32; off > 0; off >>= 1) {
      s  += __shfl_down(s, off);
      s2 += __shfl_down(s2, off);
    }
    __shared__ float ss[4], ss2[4];
    int wid = tid >> 6, lane = tid & 63;
    if (lane == 0) { ss[wid] = s; ss2[wid] = s2; }
    __syncthreads();
    if (tid == 0) {
      float a  = ss[0] + ss[1] + ss[2] + ss[3];
      float a2 = ss2[0] + ss2[1] + ss2[2] + ss2[3];
      ss[0]  = a  * (1.0f / D_);
      ss2[0] = a2 * (1.0f / D_);
    }
    __syncthreads();
    float mu = ss[0];
    float var = ss2[0] - mu * mu;
    float rstd = rsqrtf(var + 1e-5f);
    float4 wv = ((const float4*)w)[tid];
    float4 bv = ((const float4*)b)[tid];
    ushort4 o;
    o.x = f2bf((v.x - mu) * rstd * wv.x + bv.x);
    o.y = f2bf((v.y - mu) * rstd * wv.y + bv.y);
    o.z = f2bf((v.z - mu) * rstd * wv.z + bv.z);
    o.w = f2bf((v.w - mu) * rstd * wv.w + bv.w);
    ((ushort4*)(xn_b + (size_t)row * D_))[tid] = o;
    return;
  }
  int i = (blockIdx.x - 2048) * 256 + threadIdx.x;
  if (i < N4_WIN) {
    float4 v = ((const float4*)W_in)[i];
    ushort4 o; o.x = f2bf(v.x); o.y = f2bf(v.y); o.z = f2bf(v.z); o.w = f2bf(v.w);
    ((ushort4*)Win_b)[i] = o;
    return;
  }
  i -= N4_WIN;
  if (i < N4_WOUT) {
    float4 v = ((const float4*)W_out)[i];
    ushort4 o; o.x = f2bf(v.x); o.y = f2bf(v.y); o.z = f2bf(v.z); o.w = f2bf(v.w);
    ((ushort4*)Wout_b)[i] = o;
    return;
  }
  i -= N4_WOUT;
  if (i < N4_WDT) {
    float4 v = ((const float4*)W_dt)[i];
    ushort4 o; o.x = f2bf(v.x); o.y = f2bf(v.y); o.z = f2bf(v.z); o.w = f2bf(v.w);
    ((ushort4*)Wdt_b)[i] = o;
    return;
  }
  i -= N4_WDT;
  if (i < N4_WXP) {
    int row = (i * 4) >> 11;
    ushort4 o = make_ushort4(0, 0, 0, 0);
    if (row < 96) {
      float4 v = ((const float4*)W_xp)[i];
      o.x = f2bf(v.x); o.y = f2bf(v.y); o.z = f2bf(v.z); o.w = f2bf(v.w);
    }
    ((ushort4*)Wxp_b)[i] = o;
  }
}

// ---------------- bf16 MFMA GEMM: C[M][N] = A[M][K] * B[N][K]^T ----------------
// BMT x 128 tile, 256 thr (4 waves 2x2), BK=64, global_load_lds(16B) staging,
// XOR swizzle (linear LDS dest + inverse-swizzled global source + swizzled read),
// XCD-aware block swizzle (requires nwg % 8 == 0 — all our grids qualify).
// EPI: 1 = bf16 C; 2 = fp32 C + ep0 residual;
//      4 = split-K partial (grid.z slices K/16, out to Cf + z*zstride);
//      5 = bf16 C = softplus(v + ep0[c])   (delta path)
template<int EPI, int BMT>
__global__ __launch_bounds__(256) void gemm_mfma(const unsigned short* __restrict__ A, int lda,
                                                 const unsigned short* __restrict__ B, int ldb,
                                                 float* __restrict__ Cf,
                                                 unsigned short* __restrict__ Cb,
                                                 int ldc, int Nguard, int K,
                                                 const float* __restrict__ ep0,
                                                 size_t zstride = 0) {
  __shared__ unsigned short As[BMT * 64];
  __shared__ unsigned short Bs[128 * 64];
  const int tid = threadIdx.x;
  const int lane = tid & 63;
  const int w = tid >> 6;
  const int wr = w >> 1, wc = w & 1;
  // XCD-aware swizzle on the (x,y) plane
  int flat = blockIdx.y * gridDim.x + blockIdx.x;
  int nwg = gridDim.x * gridDim.y;
  int q8 = nwg >> 3;
  int swz = (flat & 7) * q8 + (flat >> 3);
  const int bm = (swz / gridDim.x) * BMT;
  const int bn = (swz % gridDim.x) * 128;
  const int l16 = lane & 15;
  constexpr int MW = BMT / 32;           // M-frags per wave

  int kbeg = 0, kend = K;
  if (EPI == 4) {
    int ks = K >> 4;
    kbeg = blockIdx.z * ks;
    kend = kbeg + ks;
    Cf += (size_t)blockIdx.z * zstride;
  }

  f32x4 acc[MW][4];
  #pragma unroll
  for (int m = 0; m < MW; ++m)
    #pragma unroll
    for (int n = 0; n < 4; ++n) acc[m][n] = (f32x4){0.f, 0.f, 0.f, 0.f};

  for (int k0 = kbeg; k0 < kend; k0 += 64) {
    // stage A tile: linear LDS dest, inverse-swizzled global column
    #pragma unroll
    for (int i = 0; i < BMT / 32; ++i) {
      int p = (i * 256 + tid) * 16;        // linear byte offset in tile
      int r = p >> 7;                      // 128 B per row
      int s = (p >> 4) & 7;                // 16B slot in row
      int cb = ((s ^ (r & 7)) << 3);       // swizzled source element col
      const unsigned short* ga = A + (size_t)(bm + r) * lda + k0 + cb;
      __builtin_amdgcn_global_load_lds(
          (const __attribute__((address_space(1))) void*)ga,
          (__attribute__((address_space(3))) void*)(As + (p >> 1)), 16, 0, 0);
    }
    #pragma unroll
    for (int i = 0; i < 4; ++i) {
      int p = (i * 256 + tid) * 16;
      int r = p >> 7;
      int s = (p >> 4) & 7;
      int cb = ((s ^ (r & 7)) << 3);
      const unsigned short* gb = B + (size_t)(bn + r) * ldb + k0 + cb;
      __builtin_amdgcn_global_load_lds(
          (const __attribute__((address_space(1))) void*)gb,
          (__attribute__((address_space(3))) void*)(Bs + (p >> 1)), 16, 0, 0);
    }
    __syncthreads();
    #pragma unroll
    for (int ks = 0; ks < 2; ++ks) {
      const int slot = ks * 4 + (lane >> 4);
      bf16x8 af[MW], bfr[4];
      #pragma unroll
      for (int m = 0; m < MW; ++m) {
        int ar = wr * (BMT / 2) + m * 16 + l16;
        af[m] = *(const bf16x8*)(As + ar * 64 + ((slot ^ (ar & 7)) << 3));
      }
      #pragma unroll
      for (int n = 0; n < 4; ++n) {
        int br = wc * 64 + n * 16 + l16;
        bfr[n] = *(const bf16x8*)(Bs + br * 64 + ((slot ^ (br & 7)) << 3));
      }
      #pragma unroll
      for (int m = 0; m < MW; ++m)
        #pragma unroll
        for (int n = 0; n < 4; ++n)
          acc[m][n] = __builtin_amdgcn_mfma_f32_16x16x32_bf16(af[m], bfr[n], acc[m][n], 0, 0, 0);
    }
    __syncthreads();
  }

  // epilogue: C row = (lane>>4)*4 + reg, col = lane&15 per fragment
  const int crow0 = bm + wr * (BMT / 2) + (lane >> 4) * 4;
  const int ccol0 = bn + wc * 64 + l16;
  #pragma unroll
  for (int m = 0; m < MW; ++m) {
    #pragma unroll
    for (int n = 0; n < 4; ++n) {
      int c = ccol0 + n * 16;
      if (c >= Nguard) continue;
      #pragma unroll
      for (int r = 0; r < 4; ++r) {
        int rr = crow0 + m * 16 + r;
        float v = acc[m][n][r];
        if (EPI == 1) {
          Cb[(size_t)rr * ldc + c] = f2bf(v);
        } else if (EPI == 2) {
          Cf[(size_t)rr * ldc + c] = v + ep0[(size_t)rr * ldc + c];
        } else if (EPI == 5) {
          Cb[(size_t)rr * ldc + c] = f2bf(softplus_f(v + ep0[c]));
        } else {
          Cf[(size_t)rr * ldc + c] = v;
        }
      }
    }
  }
}

// ---------------- split-K reduce for dbl (+ bf16 dt_low extract) ----------------
__global__ __launch_bounds__(256) void reduce_dbl_kernel(const float* __restrict__ part,
                                                         float* __restrict__ dblb,
                                                         unsigned short* __restrict__ dtlow_b) {
  int i = blockIdx.x * 256 + threadIdx.x;    // 49152 float4s
  float4 a = ((const float4*)part)[i];
  #pragma unroll
  for (int s = 1; s < 16; ++s) {
    float4 b = ((const float4*)part)[s * 49152 + i];
    a.x += b.x; a.y += b.y; a.z += b.z; a.w += b.w;
  }
  ((float4*)dblb)[i] = a;
  int flat = i * 4;
  int row = flat / 96;
  int col = flat - row * 96;
  if (col < 64) {
    ushort4 o; o.x = f2bf(a.x); o.y = f2bf(a.y); o.z = f2bf(a.z); o.w = f2bf(a.w);
    *(ushort4*)(dtlow_b + (size_t)row * 64 + col) = o;
  }
}

// ---------------- Conv1d (depthwise, K=4, causal) + SiLU, bf16 in/out --------
__global__ __launch_bounds__(256) void conv_silu_kernel(const unsigned short* __restrict__ xz,
                                                        const float* __restrict__ Wc,
                                                        const float* __restrict__ bc,
                                                        unsigned short* __restrict__ xcb) {
  int idx = blockIdx.x * 256 + threadIdx.x;   // (b*L+t)*D_INNER + e
  int e = idx & (D_INNER - 1);
  int t = (idx >> 11) & (L_ - 1);
  int bt = idx >> 11;                         // b*L + t
  float acc = bc[e];
  float w0 = Wc[e * 4 + 0], w1 = Wc[e * 4 + 1], w2 = Wc[e * 4 + 2], w3 = Wc[e * 4 + 3];
  const unsigned short* base = xz + (size_t)bt * 4096 + e;   // xs half of xz row
  if (t >= 3) acc = fmaf(bf2f(base[-3 * 4096]), w0, acc);
  if (t >= 2) acc = fmaf(bf2f(base[-2 * 4096]), w1, acc);
  if (t >= 1) acc = fmaf(bf2f(base[-1 * 4096]), w2, acc);
  acc = fmaf(bf2f(base[0]), w3, acc);
  float s = acc / (1.0f + __expf(-acc));
  xcb[idx] = f2bf(s);
}

// ---------------- Scan phase 1: per-chunk (prod dA, local state) ----------------
__global__ __launch_bounds__(256) void scan1_kernel(const unsigned short* __restrict__ delta,
                                                    const unsigned short* __restrict__ xc,
                                                    const float* __restrict__ dbl,
                                                    const float* __restrict__ A_log,
                                                    float* __restrict__ P,
                                                    float* __restrict__ Q) {
  int e = blockIdx.x * 256 + threadIdx.x;
  int b = blockIdx.y, c = blockIdx.z;
  const int t0 = (int)(b * L_ + c * LC);

  __shared__ float sB[LC][N_STATE];     // 1 KB
  {
    int step = threadIdx.x >> 4, n = threadIdx.x & 15;
    sB[step][n] = dbl[(size_t)(t0 + step) * 96 + 64 + n];
  }
  __syncthreads();

  float An[N_STATE];
  #pragma unroll
  for (int q = 0; q < 4; ++q) {
    float4 v = *(const float4*)&A_log[(size_t)e * N_STATE + q * 4];
    An[q*4+0] = -__expf(v.x); An[q*4+1] = -__expf(v.y);
    An[q*4+2] = -__expf(v.z); An[q*4+3] = -__expf(v.w);
  }
  float h[N_STATE], p[N_STATE];
  #pragma unroll
  for (int n = 0; n < N_STATE; ++n) { h[n] = 0.f; p[n] = 1.f; }

  const size_t row0 = (size_t)t0 * D_INNER + e;
  float dlt = bf2f(delta[row0]);
  float xcv = bf2f(xc[row0]);

  for (int tt = 0; tt < LC; ++tt) {
    float ndlt = 0.f, nxcv = 0.f;
    if (tt + 1 < LC) {
      ndlt = bf2f(delta[row0 + (size_t)(tt + 1) * D_INNER]);
      nxcv = bf2f(xc[row0 + (size_t)(tt + 1) * D_INNER]);
    }
    float dbx = dlt * xcv;
    #pragma unroll
    for (int n = 0; n < N_STATE; ++n) {
      float da = __expf(dlt * An[n]);
      h[n] = fmaf(da, h[n], dbx * sB[tt][n]);
      p[n] *= da;
    }
    dlt = ndlt; xcv = nxcv;
  }
  size_t o = ((size_t)(c * B_ + b) * N_STATE) * D_INNER + e;
  #pragma unroll
  for (int n = 0; n < N_STATE; ++n) {
    P[o + (size_t)n * D_INNER] = p[n];
    Q[o + (size_t)n * D_INNER] = h[n];
  }
}

// ---------------- Scan phase 2: combine chunk states (Hinit in-place in Q) ----
__global__ __launch_bounds__(256) void scan2_kernel(const float* __restrict__ P,
                                                    float* __restrict__ Q) {
  int idx = blockIdx.x * 256 + threadIdx.x;  // B_*N_STATE*D_INNER = 65536
  float H = 0.f;
  #pragma unroll
  for (int c = 0; c < NC; ++c) {
    size_t o = (size_t)c * (B_ * N_STATE * D_INNER) + idx;
    float p = P[o], q = Q[o];
    Q[o] = H;                         // Hinit for chunk c
    H = fmaf(p, H, q);
  }
}

// ---------------- Scan phase 3: replay + fused gate -> y (bf16) ----------------
__global__ __launch_bounds__(256) void scan3_kernel(const unsigned short* __restrict__ delta,
                                                    const unsigned short* __restrict__ xc,
                                                    const float* __restrict__ dbl,
                                                    const float* __restrict__ A_log,
                                                    const float* __restrict__ Hinit,
                                                    const unsigned short* __restrict__ xz,
                                                    const float* __restrict__ Dsk,
                                                    unsigned short* __restrict__ y) {
  int e = blockIdx.x * 256 + threadIdx.x;
  int b = blockIdx.y, c = blockIdx.z;
  const int t0 = (int)(b * L_ + c * LC);

  __shared__ float sB[LC][N_STATE];     // 1 KB
  __shared__ float sC[LC][N_STATE];     // 1 KB
  {
    int step = threadIdx.x >> 4, n = threadIdx.x & 15;
    const float* row = dbl + (size_t)(t0 + step) * 96;
    sB[step][n] = row[64 + n];
    sC[step][n] = row[80 + n];
  }
  __syncthreads();

  float An[N_STATE];
  #pragma unroll
  for (int q = 0; q < 4; ++q) {
    float4 v = *(const float4*)&A_log[(size_t)e * N_STATE + q * 4];
    An[q*4+0] = -__expf(v.x); An[q*4+1] = -__expf(v.y);
    An[q*4+2] = -__expf(v.z); An[q*4+3] = -__expf(v.w);
  }
  float h[N_STATE];
  {
    size_t o = ((size_t)(c * B_ + b) * N_STATE) * D_INNER + e;
    #pragma unroll
    for (int n = 0; n < N_STATE; ++n) h[n] = Hinit[o + (size_t)n * D_INNER];
  }
  float dskip = Dsk[e];
  const size_t row0 = (size_t)t0 * D_INNER + e;
  const size_t zrow0 = (size_t)t0 * 4096 + D_INNER + e;

  float dlt = bf2f(delta[row0]);
  float xcv = bf2f(xc[row0]);
  float zv  = bf2f(xz[zrow0]);

  for (int tt = 0; tt < LC; ++tt) {
    float ndlt = 0.f, nxcv = 0.f, nzv = 0.f;
    if (tt + 1 < LC) {
      ndlt = bf2f(delta[row0 + (size_t)(tt + 1) * D_INNER]);
      nxcv = bf2f(xc[row0 + (size_t)(tt + 1) * D_INNER]);
      nzv  = bf2f(xz[zrow0 + (size_t)(tt + 1) * 4096]);
    }
    float dbx = dlt * xcv;
    float yv = 0.f;
    #pragma unroll
    for (int n = 0; n < N_STATE; ++n) {
      float da = __expf(dlt * An[n]);
      h[n] = fmaf(da, h[n], dbx * sB[tt][n]);
      yv = fmaf(h[n], sC[tt][n], yv);
    }
    float gate = zv / (1.0f + __expf(-zv));
    y[row0 + (size_t)tt * D_INNER] = f2bf((yv + dskip * xcv) * gate);
    dlt = ndlt; xcv = nxcv; zv = nzv;
  }
}

// ---------------- launch ----------------
extern "C" void kernel_launch(void* const* d_in, const int* in_sizes, int n_in,
                              void* d_out, int out_size, void* d_ws, size_t ws_size,
                              hipStream_t stream) {
  const float* x       = (const float*)d_in[0];
  const float* ln_w    = (const float*)d_in[1];
  const float* ln_b    = (const float*)d_in[2];
  const float* W_in    = (const float*)d_in[3];
  const float* W_conv  = (const float*)d_in[4];
  const float* b_conv  = (const float*)d_in[5];
  const float* W_xproj = (const float*)d_in[6];
  const float* W_dt    = (const float*)d_in[7];
  const float* b_dt    = (const float*)d_in[8];
  const float* A_log   = (const float*)d_in[9];
  const float* D_skip  = (const float*)d_in[10];
  const float* W_out   = (const float*)d_in[11];
  float* out = (float*)d_out;

  const size_t BL = (size_t)B_ * L_;            // 2048
  // fp32 region (plain linear layout, no aliasing)
  float* dblb = (float*)d_ws;                   // 196,608 f
  float* part = dblb + 196608;                  // 3,145,728 f (16 x 2048 x 96)
  float* P    = part + 3145728;                 // 4,194,304 f (NC=64)
  float* Q    = P    + 4194304;                 // 4,194,304 f
  // bf16 region
  unsigned short* xn_b    = (unsigned short*)(Q + 4194304);
  unsigned short* Win_b   = xn_b    + 2097152;  // 4096*1024
  unsigned short* xz_b    = Win_b   + 4194304;  // 2048*4096
  unsigned short* xc_b    = xz_b    + 8388608;  // 2048*2048
  unsigned short* Wxp_b   = xc_b    + 4194304;  // 128*2048 (padded)
  unsigned short* y_b     = Wxp_b   + 262144;   // 2048*2048
  unsigned short* Wout_b  = y_b     + 4194304;  // 1024*2048
  unsigned short* dtlow_b = Wout_b  + 2097152;  // 2048*64
  unsigned short* Wdt_b   = dtlow_b + 131072;   // 2048*64
  unsigned short* delta_b = Wdt_b   + 131072;   // 2048*2048

  // 1. prep: LN + all weight converts (one launch)
  prep_kernel<<<2048 + CVT_BLOCKS, 256, 0, stream>>>(
      x, ln_w, ln_b, xn_b, W_in, W_out, W_dt, W_xproj, Win_b, Wout_b, Wdt_b, Wxp_b);
  // 2. input GEMM: xz = xn @ W_in^T  (M=2048, N=4096, K=1024), bf16 out
  gemm_mfma<1, 128><<<dim3(32, 16), 256, 0, stream>>>(
      xn_b, D_, Win_b, D_, nullptr, xz_b, 4096, 4096, D_, nullptr, 0);
  // 3. conv + silu -> xc_b (bf16)
  conv_silu_kernel<<<(BL * D_INNER) / 256, 256, 0, stream>>>(xz_b, W_conv, b_conv, xc_b);
  // 4. dbl = xc @ W_xproj^T  split-K x16 partials (N=96 padded to 128)
  gemm_mfma<4, 128><<<dim3(1, 16, 16), 256, 0, stream>>>(
      xc_b, D_INNER, Wxp_b, D_INNER, part, nullptr, 96, 96, D_INNER, nullptr,
      (size_t)2048 * 96);
  reduce_dbl_kernel<<<192, 256, 0, stream>>>(part, dblb, dtlow_b);
  // 5. delta = softplus(dt_low @ W_dt^T + b_dt) via MFMA -> bf16
  gemm_mfma<5, 128><<<dim3(16, 16), 256, 0, stream>>>(
      dtlow_b, DT_RANK, Wdt_b, DT_RANK, nullptr, delta_b, D_INNER, D_INNER, DT_RANK, b_dt, 0);
  // 6. chunked scan (NC=64, 3 kernels — proven correct)
  scan1_kernel<<<dim3(D_INNER / 256, B_, NC), 256, 0, stream>>>(delta_b, xc_b, dblb, A_log, P, Q);
  scan2_kernel<<<(B_ * N_STATE * D_INNER) / 256, 256, 0, stream>>>(P, Q);
  scan3_kernel<<<dim3(D_INNER / 256, B_, NC), 256, 0, stream>>>(delta_b, xc_b, dblb, A_log, Q,
                                                                xz_b, D_skip, y_b);
  // 7. out = y @ W_out^T + residual  (64x128 tile -> 256 blocks)
  gemm_mfma<2, 64><<<dim3(8, 32), 256, 0, stream>>>(
      y_b, D_INNER, Wout_b, D_INNER, out, nullptr, D_, D_, D_INNER, x, 0);
}